// Round 3
// baseline (499.079 us; speedup 1.0000x reference)
//
#include <hip/hip_runtime.h>
#include <hip/hip_bf16.h>
#include <stdint.h>

typedef unsigned int u32;
typedef unsigned short u16;
typedef __attribute__((ext_vector_type(8))) short s16x8;
typedef __attribute__((ext_vector_type(4))) float f32x4;

// ---------- helpers ----------
__device__ __forceinline__ float bf2f(u16 u) {
    union { u32 i; float f; } v; v.i = ((u32)u) << 16; return v.f;
}
__device__ __forceinline__ float sbf2f(short s) { return bf2f((u16)s); }
__device__ __forceinline__ u16 f2bf(float f) {
    union { float f; u32 i; } v; v.f = f;
    u32 i = v.i;
    return (u16)((i + 0x7FFFu + ((i >> 16) & 1u)) >> 16);
}
__device__ __forceinline__ float wredsum(float v) {
#pragma unroll
    for (int d = 32; d; d >>= 1) v += __shfl_xor(v, d);
    return v;
}
__device__ __forceinline__ float wredmax(float v) {
#pragma unroll
    for (int d = 32; d; d >>= 1) v = fmaxf(v, __shfl_xor(v, d));
    return v;
}
__device__ __forceinline__ float g16sum(float v) {
#pragma unroll
    for (int d = 8; d; d >>= 1) v += __shfl_xor(v, d);
    return v;
}
__device__ __forceinline__ float g16max(float v) {
#pragma unroll
    for (int d = 8; d; d >>= 1) v = fmaxf(v, __shfl_xor(v, d));
    return v;
}

// ---------- scalar-region layout (floats at ws+0) ----------
// [0] gauge_sum   [1] final scale   [4..36) S_joint[32]   [36..40) gate[4]
// [64..4160) colsumQ [4160..8256) colsumK [8256..8512) curv partials[256]

__global__ __launch_bounds__(256) void zero_k(float* sc) {
    for (int i = blockIdx.x * 256 + threadIdx.x; i < 16384; i += 16 * 256) sc[i] = 0.f;
}

// ---------- f32 -> bf16 conversion of x + 6 weight matrices into one bf16 region ----------
__global__ __launch_bounds__(256) void cvt7_k(
    const float* __restrict__ xf, const float* __restrict__ wq, const float* __restrict__ wk,
    const float* __restrict__ wv, const float* __restrict__ wo, const float* __restrict__ wp,
    const float* __restrict__ w1, u16* __restrict__ dst)
{
    int seg = blockIdx.y;
    const float* src; size_t off; int n;
    switch (seg) {
        case 0:  src = xf; off = 0;        n = 4194304; break;
        case 1:  src = wq; off = 4194304;  n = 1048576; break;
        case 2:  src = wk; off = 5242880;  n = 1048576; break;
        case 3:  src = wv; off = 6291456;  n = 1048576; break;
        case 4:  src = wo; off = 7340032;  n = 1048576; break;
        case 5:  src = wp; off = 8388608;  n = 1048576; break;
        default: src = w1; off = 9437184;  n = 524288;  break;
    }
    int i = (blockIdx.x * 256 + threadIdx.x) * 4;
    if (i >= n) return;
    float4 v = *(const float4*)(src + i);
    uint2 pk;
    pk.x = (u32)f2bf(v.x) | ((u32)f2bf(v.y) << 16);
    pk.y = (u32)f2bf(v.z) | ((u32)f2bf(v.w) << 16);
    *(uint2*)(dst + off + i) = pk;
}

// ---------- generic bf16 GEMM: C[M,N] = Asel[M,K] @ W[N,K]^T * s + bias ----------
// A operands bf16 (pre-converted), bias f32, C either bf16 (f32out=0) or f32 (f32out=1)
__global__ __launch_bounds__(256) void gemm_bt(
    const u16* __restrict__ A0, const u16* __restrict__ A1,
    const float* __restrict__ gsel,
    const u16* __restrict__ W, const float* __restrict__ bias,
    void* __restrict__ Cv, const float* __restrict__ scl,
    int N, int K, int relu, int f32out)
{
    __shared__ u16 As[128 * 32];
    __shared__ u16 Bs[128 * 32];
    const u16* A = A0;
    if (gsel && (gsel[0] * (1.0f / 4096.0f) > 0.3f)) A = A1;

    int t = threadIdx.x;
    int bn = blockIdx.x, bm = blockIdx.y;
    int w = t >> 6, lane = t & 63;
    int wr = (w >> 1) * 64, wc = (w & 1) * 64;
    int lr = lane & 15, lk = (lane >> 4) * 8;

    f32x4 zero4 = {0.f, 0.f, 0.f, 0.f};
    f32x4 acc[4][4];
#pragma unroll
    for (int m = 0; m < 4; m++)
#pragma unroll
        for (int n = 0; n < 4; n++) acc[m][n] = zero4;

    const u16* ga = A + (size_t)(bm * 128 + (t >> 2)) * K + (t & 3) * 8;
    const u16* gb = W + (size_t)(bn * 128 + (t >> 2)) * K + (t & 3) * 8;

    for (int k0 = 0; k0 < K; k0 += 32) {
        s16x8 a0 = *(const s16x8*)(ga + k0);
        s16x8 a1 = *(const s16x8*)(ga + (size_t)64 * K + k0);
        s16x8 b0 = *(const s16x8*)(gb + k0);
        s16x8 b1 = *(const s16x8*)(gb + (size_t)64 * K + k0);
        __syncthreads();   // previous iteration's LDS reads complete
        *(s16x8*)&As[t * 8] = a0;
        *(s16x8*)&As[2048 + t * 8] = a1;
        *(s16x8*)&Bs[t * 8] = b0;
        *(s16x8*)&Bs[2048 + t * 8] = b1;
        __syncthreads();
        s16x8 af[4], bfr[4];
#pragma unroll
        for (int m = 0; m < 4; m++) af[m] = *(const s16x8*)&As[(wr + m * 16 + lr) * 32 + lk];
#pragma unroll
        for (int n = 0; n < 4; n++) bfr[n] = *(const s16x8*)&Bs[(wc + n * 16 + lr) * 32 + lk];
#pragma unroll
        for (int m = 0; m < 4; m++)
#pragma unroll
            for (int n = 0; n < 4; n++)
                acc[m][n] = __builtin_amdgcn_mfma_f32_16x16x32_bf16(af[m], bfr[n], acc[m][n], 0, 0, 0);
    }

    float s = scl ? scl[0] : 1.0f;
    int col0 = bn * 128 + wc + lr;
    int row0 = bm * 128 + wr + (lane >> 4) * 4;
#pragma unroll
    for (int n = 0; n < 4; n++) {
        int col = col0 + n * 16;
        float bv = bias[col];
#pragma unroll
        for (int m = 0; m < 4; m++)
#pragma unroll
            for (int r = 0; r < 4; r++) {
                float v = acc[m][n][r] * s + bv;
                if (relu) v = fmaxf(v, 0.0f);
                size_t ci = (size_t)(row0 + m * 16 + r) * N + col;
                if (f32out) ((float*)Cv)[ci] = v;
                else        ((u16*)Cv)[ci] = f2bf(v);
            }
    }
}

// ---------- gauge: sum over tokens of ||x-inv||/||x|| (x is f32, INV bf16) ----------
__global__ __launch_bounds__(256) void gauge_k(const float* __restrict__ xf,
                                               const u16* __restrict__ INV, float* sc) {
    int t = threadIdx.x, w = t >> 6, lane = t & 63;
    float ssum = 0.f;
    for (int rep = 0; rep < 4; rep++) {
        size_t tok = (size_t)blockIdx.x * 16 + w * 4 + rep;
        const float4* xr = (const float4*)(xf + tok * 1024);
        const s16x8* ir = (const s16x8*)(INV + tok * 1024);
        float sr = 0.f, sx = 0.f;
#pragma unroll
        for (int c = 0; c < 2; c++) {
            s16x8 i8 = ir[lane * 2 + c];
            float4 a = xr[lane * 4 + c * 2];
            float4 b = xr[lane * 4 + c * 2 + 1];
            float xv[8] = {a.x, a.y, a.z, a.w, b.x, b.y, b.z, b.w};
#pragma unroll
            for (int e = 0; e < 8; e++) {
                float dv = xv[e] - sbf2f(i8[e]);
                sr += dv * dv; sx += xv[e] * xv[e];
            }
        }
        sr = wredsum(sr); sx = wredsum(sx);
        if (lane == 0) ssum += sqrtf(sr) / (sqrtf(sx) + 1e-8f);
    }
    if (lane == 0) atomicAdd(&sc[0], ssum);
}

// ---------- per-row: inv-norm + softmax over dk for Q and K (bf16) ----------
__global__ __launch_bounds__(256) void qksm_k(const u16* __restrict__ Qb, const u16* __restrict__ Kb,
                                              u16* __restrict__ QS, u16* __restrict__ KS,
                                              float* __restrict__ RNQ, float* __restrict__ RNK) {
    int t = threadIdx.x, w = t >> 6, lane = t & 63;
    int R = blockIdx.x * 4 + w;
    int isK = R >> 15;
    int r = R & 32767;
    const u16* src = (isK ? Kb : Qb) + (size_t)r * 128 + lane * 2;
    u32 uu = *(const u32*)src;
    float q0 = bf2f((u16)(uu & 0xffff)), q1 = bf2f((u16)(uu >> 16));
    float ss = wredsum(q0 * q0 + q1 * q1);
    float rn = 1.0f / fmaxf(sqrtf(ss), 1e-12f);
    if (lane == 0) (isK ? RNK : RNQ)[r] = rn;
    float m = wredmax(fmaxf(q0, q1));
    float e0 = __expf(q0 - m), e1 = __expf(q1 - m);
    float sum = wredsum(e0 + e1);
    float is = 1.0f / sum;
    u32 o = (u32)f2bf(e0 * is) | ((u32)f2bf(e1 * is) << 16);
    *(u32*)((isK ? KS : QS) + (size_t)r * 128 + lane * 2) = o;
}
// NOTE: Qb layout is [b][i][h*128+d]; row r above = b*8192 + h*1024 + i would MISMATCH.
// qksm_k must address [b][i][h][d]: see corrected indexing below (kept identical to r2).

// ---------- column sums of Q/K per (b,h) ----------
__global__ __launch_bounds__(256) void colsum_k(const u16* __restrict__ Qb,
                                                const u16* __restrict__ Kb, float* sc) {
    __shared__ float red[256];
    int t = threadIdx.x;
    int bx = blockIdx.x;
    int isK = bx >> 5, bh = bx & 31;
    int b = bh >> 3, h = bh & 7;
    int d = t & 127, part = t >> 7;
    const u16* src = (isK ? Kb : Qb) + ((size_t)(b * 1024 + part * 512)) * 1024 + h * 128 + d;
    float s = 0.f;
    for (int i = 0; i < 512; i++) s += bf2f(src[(size_t)i * 1024]);
    red[t] = s;
    __syncthreads();
    if (t < 128) sc[64 + isK * 4096 + bh * 128 + t] = red[t] + red[t + 128];
}

// ---------- joint entropy: sum_ij -x*log(x+1e-10), x = (Qs @ Ks^T)_ij ----------
__global__ __launch_bounds__(256) void joint_k(const u16* __restrict__ QS,
                                               const u16* __restrict__ KS, float* sc) {
    __shared__ u16 Ql[128 * 128];
    __shared__ u16 Kl[128 * 128];
    int t = threadIdx.x;
    int jt = blockIdx.x, it = blockIdx.y, bh = blockIdx.z;
    const u16* qg = QS + ((size_t)bh * 1024 + it * 128) * 128;
    const u16* kg = KS + ((size_t)bh * 1024 + jt * 128) * 128;
#pragma unroll
    for (int p = 0; p < 8; p++) {
        *(s16x8*)&Ql[p * 2048 + t * 8] = *(const s16x8*)(qg + p * 2048 + t * 8);
        *(s16x8*)&Kl[p * 2048 + t * 8] = *(const s16x8*)(kg + p * 2048 + t * 8);
    }
    __syncthreads();
    int w = t >> 6, lane = t & 63, lr = lane & 15, lk = (lane >> 4) * 8;
    int wr = (w >> 1) * 64, wc = (w & 1) * 64;
    f32x4 zero4 = {0.f, 0.f, 0.f, 0.f};
    f32x4 acc[4][4];
#pragma unroll
    for (int m = 0; m < 4; m++)
#pragma unroll
        for (int n = 0; n < 4; n++) acc[m][n] = zero4;
#pragma unroll
    for (int kk = 0; kk < 4; kk++) {
        s16x8 af[4], bfr[4];
#pragma unroll
        for (int m = 0; m < 4; m++) af[m] = *(const s16x8*)&Ql[(wr + m * 16 + lr) * 128 + kk * 32 + lk];
#pragma unroll
        for (int n = 0; n < 4; n++) bfr[n] = *(const s16x8*)&Kl[(wc + n * 16 + lr) * 128 + kk * 32 + lk];
#pragma unroll
        for (int m = 0; m < 4; m++)
#pragma unroll
            for (int n = 0; n < 4; n++)
                acc[m][n] = __builtin_amdgcn_mfma_f32_16x16x32_bf16(af[m], bfr[n], acc[m][n], 0, 0, 0);
    }
    float ts = 0.f;
#pragma unroll
    for (int m = 0; m < 4; m++)
#pragma unroll
        for (int n = 0; n < 4; n++)
#pragma unroll
            for (int r = 0; r < 4; r++) {
                float x = acc[m][n][r];
                ts += x * __logf(fmaxf(x, 0.0f) + 1e-10f);
            }
    ts = wredsum(ts);
    if (lane == 0) atomicAdd(&sc[4 + bh], -ts);
}

// ---------- gate: entropies of colsum softmax + S_ent threshold ----------
__global__ __launch_bounds__(64) void gate_k(float* sc) {
    __shared__ float Hs[64];
    int t = threadIdx.x;
    {
        const float* cs = sc + 64 + (t >> 5) * 4096 + (t & 31) * 128;
        float m = -1e30f;
        for (int d = 0; d < 128; d++) m = fmaxf(m, cs[d]);
        float Z = 0.f, E = 0.f;
        for (int d = 0; d < 128; d++) {
            float e = __expf(cs[d] - m);
            Z += e; E += e * (cs[d] - m);
        }
        Hs[t] = __logf(Z) - E / Z;
    }
    __syncthreads();
    if (t < 4) {
        float se = 0.f;
        for (int hh = 0; hh < 8; hh++)
            se += sc[4 + t * 8 + hh] - Hs[t * 8 + hh] - Hs[32 + t * 8 + hh];
        se *= 0.125f;
        sc[36 + t] = (se > 0.15f) ? 1.0f : 0.0f;
    }
}

// ---------- banded QFI attention + PV (bf16 Q/K/V, bf16 OUT) ----------
#define KVP 136
__global__ __launch_bounds__(256) void attn_k(const u16* __restrict__ Qb, const u16* __restrict__ Kb,
                                              const u16* __restrict__ Vb,
                                              const float* __restrict__ RNQ, const float* __restrict__ RNK,
                                              const float* __restrict__ sc, u16* __restrict__ OUT) {
    __shared__ u16 Kl[96 * KVP];
    __shared__ u16 Vl[96 * KVP];
    __shared__ u16 Ql[32 * 128];
    __shared__ float rkl[96];
    __shared__ float wl[16 * 66];
    int t = threadIdx.x;
    int it = blockIdx.x, h = blockIdx.y, b = blockIdx.z;
    int i0 = it * 32, jbase = i0 - 32;

    for (int c = t; c < 96 * 16; c += 256) {
        int p = c >> 4, x8 = c & 15;
        int j = jbase + p;
        s16x8 kv, vv;
        if (j >= 0 && j < 1024) {
            size_t go = ((size_t)(b * 1024 + j)) * 1024 + h * 128 + x8 * 8;
            kv = *(const s16x8*)(Kb + go);
            vv = *(const s16x8*)(Vb + go);
        } else {
#pragma unroll
            for (int e = 0; e < 8; e++) { kv[e] = 0; vv[e] = 0; }
        }
        *(s16x8*)&Kl[p * KVP + x8 * 8] = kv;
        *(s16x8*)&Vl[p * KVP + x8 * 8] = vv;
    }
    for (int c = t; c < 32 * 16; c += 256) {
        int p = c >> 4, x8 = c & 15;
        size_t go = ((size_t)(b * 1024 + i0 + p)) * 1024 + h * 128 + x8 * 8;
        *(s16x8*)&Ql[p * 128 + x8 * 8] = *(const s16x8*)(Qb + go);
    }
    if (t < 96) {
        int j = jbase + t;
        rkl[t] = (j >= 0 && j < 1024) ? RNK[((size_t)(b * 8 + h)) * 1024 + j] : 0.0f;
    }
    __syncthreads();

    float gate = sc[36 + b];
    float factor = gate / (gate + 1e-10f);
    int w = t >> 6, lane = t & 63, u = lane & 15, g = lane >> 4;

    for (int rd = 0; rd < 2; rd++) {
        int il = w * 8 + rd * 4 + g;
        int i = i0 + il;
        int jlo = max(0, i - 32), jhi = min(1023, i + 32);
        int width = jhi - jlo + 1;
        float rq = RNQ[((size_t)(b * 8 + h)) * 1024 + i];

        float sv[5];
        float mx = -1e30f;
#pragma unroll
        for (int q5 = 0; q5 < 5; q5++) {
            int sl = u + 16 * q5;
            float sval = -1e30f;
            if (sl < width) {
                int p = jlo + sl - jbase;
                float dot = 0.f;
#pragma unroll 4
                for (int d0 = 0; d0 < 128; d0 += 8) {
                    s16x8 k8 = *(const s16x8*)&Kl[p * KVP + d0];
                    s16x8 q8 = *(const s16x8*)&Ql[il * 128 + d0];
#pragma unroll
                    for (int e = 0; e < 8; e++) dot += sbf2f(q8[e]) * sbf2f(k8[e]);
                }
                float sim = dot * rq * rkl[p];
                float dd = 2.0f * (1.0f - sim);
                dd = fminf(fmaxf(dd, 0.0f), 4.0f);
                sval = -sqrtf(dd);   // scores/TEMP = -ALPHA*dist/TEMP = -dist
            }
            sv[q5] = sval;
            mx = fmaxf(mx, sval);
        }
        mx = g16max(mx);
        float se = 0.f;
#pragma unroll
        for (int q5 = 0; q5 < 5; q5++) {
            float e = (sv[q5] > -1e29f) ? __expf(sv[q5] - mx) : 0.0f;
            sv[q5] = e; se += e;
        }
        se = g16sum(se);
        float isv = 1.0f / se;
#pragma unroll
        for (int q5 = 0; q5 < 5; q5++) {
            int sl = u + 16 * q5;
            if (sl < width) wl[(w * 4 + g) * 66 + sl] = sv[q5] * isv;
        }
        __syncthreads();   // wl writes visible before PV reads

        float acc8[8];
#pragma unroll
        for (int e = 0; e < 8; e++) acc8[e] = 0.f;
        for (int sl = 0; sl < width; sl++) {
            float wj = wl[(w * 4 + g) * 66 + sl];
            int p = jlo + sl - jbase;
            s16x8 v8 = *(const s16x8*)&Vl[p * KVP + u * 8];
#pragma unroll
            for (int e = 0; e < 8; e++) acc8[e] += wj * sbf2f(v8[e]);
        }
        size_t oo = ((size_t)(b * 1024 + i)) * 1024 + h * 128 + u * 8;
        s16x8 o8;
#pragma unroll
        for (int e = 0; e < 8; e++) o8[e] = (short)f2bf(acc8[e] * factor);
        *(s16x8*)(OUT + oo) = o8;
        __syncthreads();   // PV reads done before next rd overwrites wl
    }
}

// ---------- curvature: sigmoid(h @ W2^T + b2), per-block partial sums ----------
__global__ __launch_bounds__(256) void curv_k(const u16* __restrict__ Hb, const float* __restrict__ W2,
                                              const float* __restrict__ b2, float* sc) {
    int t = threadIdx.x, w = t >> 6, lane = t & 63;
    const float4* wv4 = (const float4*)(W2 + lane * 8);
    float4 wa = wv4[0], wb = wv4[1];
    float w8[8] = {wa.x, wa.y, wa.z, wa.w, wb.x, wb.y, wb.z, wb.w};
    float csum = 0.f;
    for (int rep = 0; rep < 4; rep++) {
        size_t tok = (size_t)blockIdx.x * 16 + w * 4 + rep;
        s16x8 h8 = *(const s16x8*)(Hb + tok * 512 + lane * 8);
        float dot = 0.f;
#pragma unroll
        for (int e = 0; e < 8; e++) dot += sbf2f(h8[e]) * w8[e];
        dot = wredsum(dot);
        if (lane == 0) {
            float z = dot + b2[0];
            csum += 1.0f / (1.0f + __expf(-z));
        }
    }
    __shared__ float red[4];
    if (lane == 0) red[w] = csum;
    __syncthreads();
    if (t == 0) sc[8256 + blockIdx.x] = red[0] + red[1] + red[2] + red[3];
}

__global__ __launch_bounds__(64) void scale_k(float* sc) {
    int t = threadIdx.x;
    float s = sc[8256 + t] + sc[8256 + 64 + t] + sc[8256 + 128 + t] + sc[8256 + 192 + t];
    s = wredsum(s);
    if (t == 0) {
        float social = s * (1.0f / 4096.0f);
        float pen = __expf(-2.0f * social);     // exp(-social/TEMP), TEMP=0.5
        pen = fminf(fmaxf(pen, 0.5f), 1.5f);
        sc[1] = 1.0f - 0.3f * (1.0f - pen);     // 1 - KINDNESS_W*(1-penalty)
    }
}

// ---------- host-side launch ----------
extern "C" void kernel_launch(void* const* d_in, const int* in_sizes, int n_in,
                              void* d_out, int out_size, void* d_ws, size_t ws_size,
                              hipStream_t stream) {
    const float* xf  = (const float*)d_in[0];
    const float* Wq  = (const float*)d_in[1];
    const float* bq  = (const float*)d_in[2];
    const float* Wk  = (const float*)d_in[3];
    const float* bk_ = (const float*)d_in[4];
    const float* Wv  = (const float*)d_in[5];
    const float* bv  = (const float*)d_in[6];
    const float* Wo  = (const float*)d_in[7];
    const float* bo  = (const float*)d_in[8];
    const float* Wp  = (const float*)d_in[9];
    const float* bp  = (const float*)d_in[10];
    const float* W1  = (const float*)d_in[11];
    const float* b1  = (const float*)d_in[12];
    const float* W2  = (const float*)d_in[13];
    const float* b2  = (const float*)d_in[14];
    float* out = (float*)d_out;

    // ws layout:
    //   sc 64KB | BF region ~19.9MB (xbf + 6 bf16 weights) | INV 8MB (→QS) | Qb 8MB (→Hb)
    //   | Kb 8MB | Vb 8MB | KS 8MB (→OUTb) | RNQ/RNK 256KB   (total ≈ 63.3MB)
    uint8_t* ws = (uint8_t*)d_ws;
    float* sc  = (float*)ws;
    u16* BF    = (u16*)(ws + 0x0010000);
    u16* xbf   = BF;
    u16* Wqb   = BF + 4194304;
    u16* Wkb   = BF + 5242880;
    u16* Wvb   = BF + 6291456;
    u16* Wob   = BF + 7340032;
    u16* Wpb   = BF + 8388608;
    u16* W1b   = BF + 9437184;
    u16* INV   = (u16*)(ws + 0x1410000);
    u16* Qb    = (u16*)(ws + 0x1C10000);
    u16* Kb    = (u16*)(ws + 0x2410000);
    u16* Vb    = (u16*)(ws + 0x2C10000);
    u16* KS    = (u16*)(ws + 0x3410000);
    float* RNQ = (float*)(ws + 0x3C10000);
    float* RNK = (float*)(ws + 0x3C30000);
    u16* QS    = INV;   // INV dead after Q/K GEMMs
    u16* OUTb  = KS;    // KS dead after joint_k
    u16* Hb    = Qb;    // Qb dead after attn

    zero_k<<<16, 256, 0, stream>>>(sc);
    cvt7_k<<<dim3(4096, 7), 256, 0, stream>>>(xf, Wq, Wk, Wv, Wo, Wp, W1, BF);
    // invariant = x @ Wproj^T + bproj
    gemm_bt<<<dim3(8, 32), 256, 0, stream>>>(xbf, nullptr, nullptr, Wpb, bp, INV, nullptr, 1024, 1024, 0, 0);
    gauge_k<<<256, 256, 0, stream>>>(xf, INV, sc);
    // Q, K from x_qk = (gauge > 0.3 ? invariant : x); V from x
    gemm_bt<<<dim3(8, 32), 256, 0, stream>>>(xbf, INV, sc, Wqb, bq, Qb, nullptr, 1024, 1024, 0, 0);
    gemm_bt<<<dim3(8, 32), 256, 0, stream>>>(xbf, INV, sc, Wkb, bk_, Kb, nullptr, 1024, 1024, 0, 0);
    gemm_bt<<<dim3(8, 32), 256, 0, stream>>>(xbf, nullptr, nullptr, Wvb, bv, Vb, nullptr, 1024, 1024, 0, 0);
    // per-row norms + softmax(Q/K over dk)
    qksm_k<<<16384, 256, 0, stream>>>(Qb, Kb, QS, KS, RNQ, RNK);
    colsum_k<<<64, 256, 0, stream>>>(Qb, Kb, sc);
    // joint entanglement entropy
    joint_k<<<dim3(8, 8, 32), 256, 0, stream>>>(QS, KS, sc);
    gate_k<<<1, 64, 0, stream>>>(sc);
    // banded attention
    attn_k<<<dim3(32, 8, 4), 256, 0, stream>>>(Qb, Kb, Vb, RNQ, RNK, sc, OUTb);
    // h = relu(out @ W1^T + b1)
    gemm_bt<<<dim3(4, 32), 256, 0, stream>>>(OUTb, nullptr, nullptr, W1b, b1, Hb, nullptr, 512, 1024, 1, 0);
    curv_k<<<256, 256, 0, stream>>>(Hb, W2, b2, sc);
    scale_k<<<1, 64, 0, stream>>>(sc);
    // final = (scale * out) @ Wo^T + bo  (f32 output)
    gemm_bt<<<dim3(8, 32), 256, 0, stream>>>(OUTb, nullptr, nullptr, Wob, bo, out, sc + 1, 1024, 1024, 0, 1);
    (void)in_sizes; (void)n_in; (void)out_size; (void)ws_size;
}

// Round 4
// 392.302 us; speedup vs baseline: 1.2722x; 1.2722x over previous
//
#include <hip/hip_runtime.h>
#include <hip/hip_bf16.h>
#include <stdint.h>

typedef unsigned int u32;
typedef unsigned short u16;
typedef __attribute__((ext_vector_type(8))) short s16x8;
typedef __attribute__((ext_vector_type(4))) float f32x4;

// ---------- helpers ----------
__device__ __forceinline__ float bf2f(u16 u) {
    union { u32 i; float f; } v; v.i = ((u32)u) << 16; return v.f;
}
__device__ __forceinline__ float sbf2f(short s) { return bf2f((u16)s); }
__device__ __forceinline__ u16 f2bf(float f) {
    union { float f; u32 i; } v; v.f = f;
    u32 i = v.i;
    return (u16)((i + 0x7FFFu + ((i >> 16) & 1u)) >> 16);
}
__device__ __forceinline__ float wredsum(float v) {
#pragma unroll
    for (int d = 32; d; d >>= 1) v += __shfl_xor(v, d);
    return v;
}
__device__ __forceinline__ float wredmax(float v) {
#pragma unroll
    for (int d = 32; d; d >>= 1) v = fmaxf(v, __shfl_xor(v, d));
    return v;
}
__device__ __forceinline__ float g16sum(float v) {
#pragma unroll
    for (int d = 8; d; d >>= 1) v += __shfl_xor(v, d);
    return v;
}
__device__ __forceinline__ float g16max(float v) {
#pragma unroll
    for (int d = 8; d; d >>= 1) v = fmaxf(v, __shfl_xor(v, d));
    return v;
}
// async global->LDS, 16B per lane; LDS dest = wave-uniform base + lane*16
__device__ __forceinline__ void gll16(const u16* g, u16* l) {
    __builtin_amdgcn_global_load_lds((const __attribute__((address_space(1))) u32*)g,
                                     (__attribute__((address_space(3))) u32*)l,
                                     16, 0, 0);
}

// ---------- scalar-region layout (floats at ws+0) ----------
// [0] gauge_sum  [1] final scale  [4..36) S_joint[32]  [36..40) gate[4]
// [64..4160) colsumQ  [4160..8256) colsumK  [8256..8512) curv partials[256]

__global__ __launch_bounds__(256) void zero_k(float* sc) {
    for (int i = blockIdx.x * 256 + threadIdx.x; i < 16384; i += 16 * 256) sc[i] = 0.f;
}

// ---------- f32 -> bf16 conversion of x + 6 weight matrices ----------
__global__ __launch_bounds__(256) void cvt7_k(
    const float* __restrict__ xf, const float* __restrict__ wq, const float* __restrict__ wk,
    const float* __restrict__ wv, const float* __restrict__ wo, const float* __restrict__ wp,
    const float* __restrict__ w1, u16* __restrict__ dst)
{
    int seg = blockIdx.y;
    const float* src; size_t off; int n;
    switch (seg) {
        case 0:  src = xf; off = 0;        n = 4194304; break;
        case 1:  src = wq; off = 4194304;  n = 1048576; break;
        case 2:  src = wk; off = 5242880;  n = 1048576; break;
        case 3:  src = wv; off = 6291456;  n = 1048576; break;
        case 4:  src = wo; off = 7340032;  n = 1048576; break;
        case 5:  src = wp; off = 8388608;  n = 1048576; break;
        default: src = w1; off = 9437184;  n = 524288;  break;
    }
    int i = (blockIdx.x * 256 + threadIdx.x) * 4;
    if (i >= n) return;
    float4 v = *(const float4*)(src + i);
    uint2 pk;
    pk.x = (u32)f2bf(v.x) | ((u32)f2bf(v.y) << 16);
    pk.y = (u32)f2bf(v.z) | ((u32)f2bf(v.w) << 16);
    *(uint2*)(dst + off + i) = pk;
}

// ---------- generic bf16 GEMM (gll16-staged): C[M,N] = A[M,K] @ W[N,K]^T * s + bias ----------
__global__ __launch_bounds__(256) void gemm_bt(
    const u16* __restrict__ A0, const u16* __restrict__ A1,
    const float* __restrict__ gsel,
    const u16* __restrict__ W, const float* __restrict__ bias,
    void* __restrict__ Cv, const float* __restrict__ scl,
    int N, int K, int relu, int f32out)
{
    __shared__ u16 As[128 * 32];
    __shared__ u16 Bs[128 * 32];
    const u16* A = A0;
    if (gsel && (gsel[0] * (1.0f / 4096.0f) > 0.3f)) A = A1;

    int t = threadIdx.x;
    int bn = blockIdx.x, bm = blockIdx.y;
    int w = t >> 6, lane = t & 63;
    int wr = (w >> 1) * 64, wc = (w & 1) * 64;
    int lr = lane & 15, lk = (lane >> 4) * 8;

    f32x4 zero4 = {0.f, 0.f, 0.f, 0.f};
    f32x4 acc[4][4];
#pragma unroll
    for (int m = 0; m < 4; m++)
#pragma unroll
        for (int n = 0; n < 4; n++) acc[m][n] = zero4;

    const u16* ga = A + (size_t)(bm * 128 + (t >> 2)) * K + (t & 3) * 8;
    const u16* gb = W + (size_t)(bn * 128 + (t >> 2)) * K + (t & 3) * 8;

    for (int k0 = 0; k0 < K; k0 += 32) {
        __syncthreads();   // prior iter's LDS reads done
        gll16(ga + k0, As + t * 8);
        gll16(ga + k0 + (size_t)64 * K, As + 2048 + t * 8);
        gll16(gb + k0, Bs + t * 8);
        gll16(gb + k0 + (size_t)64 * K, Bs + 2048 + t * 8);
        __syncthreads();   // drains vmcnt -> staged data visible
        s16x8 af[4], bfr[4];
#pragma unroll
        for (int m = 0; m < 4; m++) af[m] = *(const s16x8*)&As[(wr + m * 16 + lr) * 32 + lk];
#pragma unroll
        for (int n = 0; n < 4; n++) bfr[n] = *(const s16x8*)&Bs[(wc + n * 16 + lr) * 32 + lk];
#pragma unroll
        for (int m = 0; m < 4; m++)
#pragma unroll
            for (int n = 0; n < 4; n++)
                acc[m][n] = __builtin_amdgcn_mfma_f32_16x16x32_bf16(af[m], bfr[n], acc[m][n], 0, 0, 0);
    }

    float s = scl ? scl[0] : 1.0f;
    int col0 = bn * 128 + wc + lr;
    int row0 = bm * 128 + wr + (lane >> 4) * 4;
#pragma unroll
    for (int n = 0; n < 4; n++) {
        int col = col0 + n * 16;
        float bv = bias[col];
#pragma unroll
        for (int m = 0; m < 4; m++)
#pragma unroll
            for (int r = 0; r < 4; r++) {
                float v = acc[m][n][r] * s + bv;
                if (relu) v = fmaxf(v, 0.0f);
                size_t ci = (size_t)(row0 + m * 16 + r) * N + col;
                if (f32out) ((float*)Cv)[ci] = v;
                else        ((u16*)Cv)[ci] = f2bf(v);
            }
    }
}

// ---------- fused QKV GEMM: N=3072 (Wq|Wk|Wv rows contiguous in BF region) ----------
__global__ __launch_bounds__(256) void gemm_qkv(
    const u16* __restrict__ X, const u16* __restrict__ INV,
    const float* __restrict__ gsel,
    const u16* __restrict__ Wqkv,
    const float* __restrict__ bq, const float* __restrict__ bk, const float* __restrict__ bv,
    u16* __restrict__ Qb, u16* __restrict__ Kb, u16* __restrict__ Vb)
{
    const int K = 1024;
    __shared__ u16 As[128 * 32];
    __shared__ u16 Bs[128 * 32];
    int t = threadIdx.x;
    int bn = blockIdx.x, bm = blockIdx.y;
    int reg = bn >> 3;   // 0=Q 1=K 2=V
    const u16* A = (reg == 2) ? X : ((gsel[0] * (1.0f / 4096.0f) > 0.3f) ? INV : X);
    const float* bias = (reg == 0) ? bq : (reg == 1) ? bk : bv;
    u16* C = (reg == 0) ? Qb : (reg == 1) ? Kb : Vb;

    int w = t >> 6, lane = t & 63;
    int wr = (w >> 1) * 64, wc = (w & 1) * 64;
    int lr = lane & 15, lk = (lane >> 4) * 8;

    f32x4 zero4 = {0.f, 0.f, 0.f, 0.f};
    f32x4 acc[4][4];
#pragma unroll
    for (int m = 0; m < 4; m++)
#pragma unroll
        for (int n = 0; n < 4; n++) acc[m][n] = zero4;

    const u16* ga = A + (size_t)(bm * 128 + (t >> 2)) * K + (t & 3) * 8;
    const u16* gb = Wqkv + (size_t)(bn * 128 + (t >> 2)) * K + (t & 3) * 8;

    for (int k0 = 0; k0 < K; k0 += 32) {
        __syncthreads();
        gll16(ga + k0, As + t * 8);
        gll16(ga + k0 + (size_t)64 * K, As + 2048 + t * 8);
        gll16(gb + k0, Bs + t * 8);
        gll16(gb + k0 + (size_t)64 * K, Bs + 2048 + t * 8);
        __syncthreads();
        s16x8 af[4], bfr[4];
#pragma unroll
        for (int m = 0; m < 4; m++) af[m] = *(const s16x8*)&As[(wr + m * 16 + lr) * 32 + lk];
#pragma unroll
        for (int n = 0; n < 4; n++) bfr[n] = *(const s16x8*)&Bs[(wc + n * 16 + lr) * 32 + lk];
#pragma unroll
        for (int m = 0; m < 4; m++)
#pragma unroll
            for (int n = 0; n < 4; n++)
                acc[m][n] = __builtin_amdgcn_mfma_f32_16x16x32_bf16(af[m], bfr[n], acc[m][n], 0, 0, 0);
    }

    int col0 = (bn & 7) * 128 + wc + lr;
    int row0 = bm * 128 + wr + (lane >> 4) * 4;
#pragma unroll
    for (int n = 0; n < 4; n++) {
        int col = col0 + n * 16;
        float bv = bias[col];
#pragma unroll
        for (int m = 0; m < 4; m++)
#pragma unroll
            for (int r = 0; r < 4; r++)
                C[(size_t)(row0 + m * 16 + r) * 1024 + col] = f2bf(acc[m][n][r] + bv);
    }
}

// ---------- gauge: sum over tokens of ||x-inv||/||x|| ----------
__global__ __launch_bounds__(256) void gauge_k(const float* __restrict__ xf,
                                               const u16* __restrict__ INV, float* sc) {
    int t = threadIdx.x, w = t >> 6, lane = t & 63;
    float ssum = 0.f;
    for (int rep = 0; rep < 4; rep++) {
        size_t tok = (size_t)blockIdx.x * 16 + w * 4 + rep;
        const float4* xr = (const float4*)(xf + tok * 1024);
        const s16x8* ir = (const s16x8*)(INV + tok * 1024);
        float sr = 0.f, sx = 0.f;
#pragma unroll
        for (int c = 0; c < 2; c++) {
            s16x8 i8 = ir[lane * 2 + c];
            float4 a = xr[lane * 4 + c * 2];
            float4 b = xr[lane * 4 + c * 2 + 1];
            float xv[8] = {a.x, a.y, a.z, a.w, b.x, b.y, b.z, b.w};
#pragma unroll
            for (int e = 0; e < 8; e++) {
                float dv = xv[e] - sbf2f(i8[e]);
                sr += dv * dv; sx += xv[e] * xv[e];
            }
        }
        sr = wredsum(sr); sx = wredsum(sx);
        if (lane == 0) ssum += sqrtf(sr) / (sqrtf(sx) + 1e-8f);
    }
    if (lane == 0) atomicAdd(&sc[0], ssum);
}

// ---------- per-row inv-norm + softmax(dk) for Q,K ----------
// physical chunk r of Qb ([b][i][h] order) -> logical L = [b][h][i] for RNQ/QS
__global__ __launch_bounds__(256) void qksm_k(const u16* __restrict__ Qb, const u16* __restrict__ Kb,
                                              u16* __restrict__ QS, u16* __restrict__ KS,
                                              float* __restrict__ RNQ, float* __restrict__ RNK) {
    int t = threadIdx.x, w = t >> 6, lane = t & 63;
    int R = blockIdx.x * 4 + w;
    int isK = R >> 15;
    int r = R & 32767;
    int b = r >> 13, i = (r >> 3) & 1023, h = r & 7;
    int L = b * 8192 + h * 1024 + i;
    const u16* src = (isK ? Kb : Qb) + (size_t)r * 128 + lane * 2;
    u32 uu = *(const u32*)src;
    float q0 = bf2f((u16)(uu & 0xffff)), q1 = bf2f((u16)(uu >> 16));
    float ss = wredsum(q0 * q0 + q1 * q1);
    float rn = 1.0f / fmaxf(sqrtf(ss), 1e-12f);
    if (lane == 0) (isK ? RNK : RNQ)[L] = rn;
    float m = wredmax(fmaxf(q0, q1));
    float e0 = __expf(q0 - m), e1 = __expf(q1 - m);
    float sum = wredsum(e0 + e1);
    float is = 1.0f / sum;
    u32 o = (u32)f2bf(e0 * is) | ((u32)f2bf(e1 * is) << 16);
    *(u32*)((isK ? KS : QS) + (size_t)L * 128 + lane * 2) = o;
}

// ---------- column sums of Q/K per (b,h), i split 8 ways ----------
__global__ __launch_bounds__(256) void colsum_k(const u16* __restrict__ Qb,
                                                const u16* __restrict__ Kb, float* sc) {
    __shared__ float red[256];
    int t = threadIdx.x;
    int bx = blockIdx.x, chunk = blockIdx.y;
    int isK = bx >> 5, bh = bx & 31;
    int b = bh >> 3, h = bh & 7;
    int d = t & 127, part = t >> 7;
    int ibase = chunk * 128 + part * 64;
    const u16* src = (isK ? Kb : Qb) + ((size_t)(b * 1024 + ibase)) * 1024 + h * 128 + d;
    float s = 0.f;
    for (int i = 0; i < 64; i++) s += bf2f(src[(size_t)i * 1024]);
    red[t] = s;
    __syncthreads();
    if (t < 128) atomicAdd(&sc[64 + isK * 4096 + bh * 128 + t], red[t] + red[t + 128]);
}

// ---------- joint entropy, no-LDS reg-fragment GEMM ----------
// H_joint needs only sum(x*log x) -> fragments loaded straight from global (L2-resident)
__global__ __launch_bounds__(256) void joint_k(const u16* __restrict__ QS,
                                               const u16* __restrict__ KS, float* sc) {
    __shared__ float red[4];
    int t = threadIdx.x;
    int jt = blockIdx.x, it = blockIdx.y, bh = blockIdx.z;
    int w = t >> 6, lane = t & 63, lr = lane & 15;
    int lk = (lane >> 4) * 8;
    int wr = (w >> 1) * 64, wc = (w & 1) * 64;
    const u16* qg = QS + ((size_t)bh * 1024 + it * 128) * 128;
    const u16* kg = KS + ((size_t)bh * 1024 + jt * 128) * 128;

    f32x4 zero4 = {0.f, 0.f, 0.f, 0.f};
    f32x4 acc[4][4];
#pragma unroll
    for (int m = 0; m < 4; m++)
#pragma unroll
        for (int n = 0; n < 4; n++) acc[m][n] = zero4;
#pragma unroll
    for (int kk = 0; kk < 4; kk++) {
        s16x8 af[4], bfr[4];
#pragma unroll
        for (int m = 0; m < 4; m++)
            af[m] = *(const s16x8*)(qg + (size_t)(wr + m * 16 + lr) * 128 + kk * 32 + lk);
#pragma unroll
        for (int n = 0; n < 4; n++)
            bfr[n] = *(const s16x8*)(kg + (size_t)(wc + n * 16 + lr) * 128 + kk * 32 + lk);
#pragma unroll
        for (int m = 0; m < 4; m++)
#pragma unroll
            for (int n = 0; n < 4; n++)
                acc[m][n] = __builtin_amdgcn_mfma_f32_16x16x32_bf16(af[m], bfr[n], acc[m][n], 0, 0, 0);
    }
    float ts = 0.f;
#pragma unroll
    for (int m = 0; m < 4; m++)
#pragma unroll
        for (int n = 0; n < 4; n++)
#pragma unroll
            for (int r = 0; r < 4; r++) {
                float x = acc[m][n][r];
                ts += x * __logf(fmaxf(x, 0.0f) + 1e-10f);
            }
    ts = wredsum(ts);
    if (lane == 0) red[w] = ts;
    __syncthreads();
    if (t == 0) atomicAdd(&sc[4 + bh], -(red[0] + red[1] + red[2] + red[3]));
}

// ---------- gate ----------
__global__ __launch_bounds__(64) void gate_k(float* sc) {
    __shared__ float Hs[64];
    int t = threadIdx.x;
    {
        const float* cs = sc + 64 + (t >> 5) * 4096 + (t & 31) * 128;
        float m = -1e30f;
        for (int d = 0; d < 128; d++) m = fmaxf(m, cs[d]);
        float Z = 0.f, E = 0.f;
        for (int d = 0; d < 128; d++) {
            float e = __expf(cs[d] - m);
            Z += e; E += e * (cs[d] - m);
        }
        Hs[t] = __logf(Z) - E / Z;
    }
    __syncthreads();
    if (t < 4) {
        float se = 0.f;
        for (int hh = 0; hh < 8; hh++)
            se += sc[4 + t * 8 + hh] - Hs[t * 8 + hh] - Hs[32 + t * 8 + hh];
        se *= 0.125f;
        sc[36 + t] = (se > 0.15f) ? 1.0f : 0.0f;
    }
}

// ---------- banded QFI attention + PV ----------
#define KVP 136
__global__ __launch_bounds__(256) void attn_k(const u16* __restrict__ Qb, const u16* __restrict__ Kb,
                                              const u16* __restrict__ Vb,
                                              const float* __restrict__ RNQ, const float* __restrict__ RNK,
                                              const float* __restrict__ sc, u16* __restrict__ OUT) {
    __shared__ u16 Kl[96 * KVP];
    __shared__ u16 Vl[96 * KVP];
    __shared__ u16 Ql[32 * 128];
    __shared__ float rkl[96];
    __shared__ float wl[16 * 66];
    int t = threadIdx.x;
    int it = blockIdx.x, h = blockIdx.y, b = blockIdx.z;
    int i0 = it * 32, jbase = i0 - 32;

    for (int c = t; c < 96 * 16; c += 256) {
        int p = c >> 4, x8 = c & 15;
        int j = jbase + p;
        s16x8 kv, vv;
        if (j >= 0 && j < 1024) {
            size_t go = ((size_t)(b * 1024 + j)) * 1024 + h * 128 + x8 * 8;
            kv = *(const s16x8*)(Kb + go);
            vv = *(const s16x8*)(Vb + go);
        } else {
#pragma unroll
            for (int e = 0; e < 8; e++) { kv[e] = 0; vv[e] = 0; }
        }
        *(s16x8*)&Kl[p * KVP + x8 * 8] = kv;
        *(s16x8*)&Vl[p * KVP + x8 * 8] = vv;
    }
    for (int c = t; c < 32 * 16; c += 256) {
        int p = c >> 4, x8 = c & 15;
        size_t go = ((size_t)(b * 1024 + i0 + p)) * 1024 + h * 128 + x8 * 8;
        *(s16x8*)&Ql[p * 128 + x8 * 8] = *(const s16x8*)(Qb + go);
    }
    if (t < 96) {
        int j = jbase + t;
        rkl[t] = (j >= 0 && j < 1024) ? RNK[((size_t)(b * 8 + h)) * 1024 + j] : 0.0f;
    }
    __syncthreads();

    float gate = sc[36 + b];
    float factor = gate / (gate + 1e-10f);
    int w = t >> 6, lane = t & 63, u = lane & 15, g = lane >> 4;

    for (int rd = 0; rd < 2; rd++) {
        int il = w * 8 + rd * 4 + g;
        int i = i0 + il;
        int jlo = max(0, i - 32), jhi = min(1023, i + 32);
        int width = jhi - jlo + 1;
        float rq = RNQ[((size_t)(b * 8 + h)) * 1024 + i];

        float sv[5];
        float mx = -1e30f;
#pragma unroll
        for (int q5 = 0; q5 < 5; q5++) {
            int sl = u + 16 * q5;
            float sval = -1e30f;
            if (sl < width) {
                int p = jlo + sl - jbase;
                float dot = 0.f;
#pragma unroll 4
                for (int d0 = 0; d0 < 128; d0 += 8) {
                    s16x8 k8 = *(const s16x8*)&Kl[p * KVP + d0];
                    s16x8 q8 = *(const s16x8*)&Ql[il * 128 + d0];
#pragma unroll
                    for (int e = 0; e < 8; e++) dot += sbf2f(q8[e]) * sbf2f(k8[e]);
                }
                float sim = dot * rq * rkl[p];
                float dd = 2.0f * (1.0f - sim);
                dd = fminf(fmaxf(dd, 0.0f), 4.0f);
                sval = -sqrtf(dd);   // scores/TEMP = -dist
            }
            sv[q5] = sval;
            mx = fmaxf(mx, sval);
        }
        mx = g16max(mx);
        float se = 0.f;
#pragma unroll
        for (int q5 = 0; q5 < 5; q5++) {
            float e = (sv[q5] > -1e29f) ? __expf(sv[q5] - mx) : 0.0f;
            sv[q5] = e; se += e;
        }
        se = g16sum(se);
        float isv = 1.0f / se;
#pragma unroll
        for (int q5 = 0; q5 < 5; q5++) {
            int sl = u + 16 * q5;
            if (sl < width) wl[(w * 4 + g) * 66 + sl] = sv[q5] * isv;
        }
        __syncthreads();

        float acc8[8];
#pragma unroll
        for (int e = 0; e < 8; e++) acc8[e] = 0.f;
        for (int sl = 0; sl < width; sl++) {
            float wj = wl[(w * 4 + g) * 66 + sl];
            int p = jlo + sl - jbase;
            s16x8 v8 = *(const s16x8*)&Vl[p * KVP + u * 8];
#pragma unroll
            for (int e = 0; e < 8; e++) acc8[e] += wj * sbf2f(v8[e]);
        }
        size_t oo = ((size_t)(b * 1024 + i)) * 1024 + h * 128 + u * 8;
        s16x8 o8;
#pragma unroll
        for (int e = 0; e < 8; e++) o8[e] = (short)f2bf(acc8[e] * factor);
        *(s16x8*)(OUT + oo) = o8;
        __syncthreads();
    }
}

// ---------- curvature ----------
__global__ __launch_bounds__(256) void curv_k(const u16* __restrict__ Hb, const float* __restrict__ W2,
                                              const float* __restrict__ b2, float* sc) {
    int t = threadIdx.x, w = t >> 6, lane = t & 63;
    const float4* wv4 = (const float4*)(W2 + lane * 8);
    float4 wa = wv4[0], wb = wv4[1];
    float w8[8] = {wa.x, wa.y, wa.z, wa.w, wb.x, wb.y, wb.z, wb.w};
    float csum = 0.f;
    for (int rep = 0; rep < 4; rep++) {
        size_t tok = (size_t)blockIdx.x * 16 + w * 4 + rep;
        s16x8 h8 = *(const s16x8*)(Hb + tok * 512 + lane * 8);
        float dot = 0.f;
#pragma unroll
        for (int e = 0; e < 8; e++) dot += sbf2f(h8[e]) * w8[e];
        dot = wredsum(dot);
        if (lane == 0) {
            float z = dot + b2[0];
            csum += 1.0f / (1.0f + __expf(-z));
        }
    }
    __shared__ float red[4];
    if (lane == 0) red[w] = csum;
    __syncthreads();
    if (t == 0) sc[8256 + blockIdx.x] = red[0] + red[1] + red[2] + red[3];
}

__global__ __launch_bounds__(64) void scale_k(float* sc) {
    int t = threadIdx.x;
    float s = sc[8256 + t] + sc[8256 + 64 + t] + sc[8256 + 128 + t] + sc[8256 + 192 + t];
    s = wredsum(s);
    if (t == 0) {
        float social = s * (1.0f / 4096.0f);
        float pen = __expf(-2.0f * social);
        pen = fminf(fmaxf(pen, 0.5f), 1.5f);
        sc[1] = 1.0f - 0.3f * (1.0f - pen);
    }
}

// ---------- host-side launch ----------
extern "C" void kernel_launch(void* const* d_in, const int* in_sizes, int n_in,
                              void* d_out, int out_size, void* d_ws, size_t ws_size,
                              hipStream_t stream) {
    const float* xf  = (const float*)d_in[0];
    const float* Wq  = (const float*)d_in[1];
    const float* bq  = (const float*)d_in[2];
    const float* Wk  = (const float*)d_in[3];
    const float* bk_ = (const float*)d_in[4];
    const float* Wv  = (const float*)d_in[5];
    const float* bv  = (const float*)d_in[6];
    const float* Wo  = (const float*)d_in[7];
    const float* bo  = (const float*)d_in[8];
    const float* Wp  = (const float*)d_in[9];
    const float* bp  = (const float*)d_in[10];
    const float* W1  = (const float*)d_in[11];
    const float* b1  = (const float*)d_in[12];
    const float* W2  = (const float*)d_in[13];
    const float* b2  = (const float*)d_in[14];
    float* out = (float*)d_out;

    uint8_t* ws = (uint8_t*)d_ws;
    float* sc  = (float*)ws;
    u16* BF    = (u16*)(ws + 0x0010000);
    u16* xbf   = BF;
    u16* Wqb   = BF + 4194304;        // Wq|Wk|Wv rows contiguous -> fused N=3072
    u16* Wob   = BF + 7340032;
    u16* Wpb   = BF + 8388608;
    u16* W1b   = BF + 9437184;
    u16* INV   = (u16*)(ws + 0x1410000);
    u16* Qb    = (u16*)(ws + 0x1C10000);
    u16* Kb    = (u16*)(ws + 0x2410000);
    u16* Vb    = (u16*)(ws + 0x2C10000);
    u16* KS    = (u16*)(ws + 0x3410000);
    float* RNQ = (float*)(ws + 0x3C10000);
    float* RNK = (float*)(ws + 0x3C30000);
    u16* QS    = INV;   // INV dead after QKV GEMM
    u16* OUTb  = KS;    // KS dead after joint_k
    u16* Hb    = Qb;    // Qb dead after attn

    zero_k<<<16, 256, 0, stream>>>(sc);
    cvt7_k<<<dim3(4096, 7), 256, 0, stream>>>(xf, Wq, Wk, Wv, Wo, Wp, W1, BF);
    gemm_bt<<<dim3(8, 32), 256, 0, stream>>>(xbf, nullptr, nullptr, Wpb, bp, INV, nullptr, 1024, 1024, 0, 0);
    gauge_k<<<256, 256, 0, stream>>>(xf, INV, sc);
    gemm_qkv<<<dim3(24, 32), 256, 0, stream>>>(xbf, INV, sc, Wqb, bq, bk_, bv, Qb, Kb, Vb);
    qksm_k<<<16384, 256, 0, stream>>>(Qb, Kb, QS, KS, RNQ, RNK);
    colsum_k<<<dim3(64, 8), 256, 0, stream>>>(Qb, Kb, sc);
    joint_k<<<dim3(8, 8, 32), 256, 0, stream>>>(QS, KS, sc);
    gate_k<<<1, 64, 0, stream>>>(sc);
    attn_k<<<dim3(32, 8, 4), 256, 0, stream>>>(Qb, Kb, Vb, RNQ, RNK, sc, OUTb);
    gemm_bt<<<dim3(4, 32), 256, 0, stream>>>(OUTb, nullptr, nullptr, W1b, b1, Hb, nullptr, 512, 1024, 1, 0);
    curv_k<<<256, 256, 0, stream>>>(Hb, W2, b2, sc);
    scale_k<<<1, 64, 0, stream>>>(sc);
    gemm_bt<<<dim3(8, 32), 256, 0, stream>>>(OUTb, nullptr, nullptr, Wob, bo, out, sc + 1, 1024, 1024, 0, 1);
    (void)in_sizes; (void)n_in; (void)out_size; (void)ws_size;
}

// Round 5
// 358.354 us; speedup vs baseline: 1.3927x; 1.0947x over previous
//
#include <hip/hip_runtime.h>
#include <hip/hip_bf16.h>
#include <stdint.h>

typedef unsigned int u32;
typedef unsigned short u16;
typedef __attribute__((ext_vector_type(8))) short s16x8;
typedef __attribute__((ext_vector_type(4))) float f32x4;

// ---------- helpers ----------
__device__ __forceinline__ float bf2f(u16 u) {
    union { u32 i; float f; } v; v.i = ((u32)u) << 16; return v.f;
}
__device__ __forceinline__ float sbf2f(short s) { return bf2f((u16)s); }
__device__ __forceinline__ u16 f2bf(float f) {
    union { float f; u32 i; } v; v.f = f;
    u32 i = v.i;
    return (u16)((i + 0x7FFFu + ((i >> 16) & 1u)) >> 16);
}
__device__ __forceinline__ float wredsum(float v) {
#pragma unroll
    for (int d = 32; d; d >>= 1) v += __shfl_xor(v, d);
    return v;
}
__device__ __forceinline__ float wredmax(float v) {
#pragma unroll
    for (int d = 32; d; d >>= 1) v = fmaxf(v, __shfl_xor(v, d));
    return v;
}
__device__ __forceinline__ float g16sum(float v) {
#pragma unroll
    for (int d = 8; d; d >>= 1) v += __shfl_xor(v, d);
    return v;
}
__device__ __forceinline__ float g16max(float v) {
#pragma unroll
    for (int d = 8; d; d >>= 1) v = fmaxf(v, __shfl_xor(v, d));
    return v;
}
// async global->LDS, 16B per lane; LDS dest = wave-uniform base + lane*16
__device__ __forceinline__ void gll16(const u16* g, u16* l) {
    __builtin_amdgcn_global_load_lds((const __attribute__((address_space(1))) u32*)g,
                                     (__attribute__((address_space(3))) u32*)l,
                                     16, 0, 0);
}

// ---------- scalar-region layout (floats at ws+0) ----------
// [0] gauge_sum  [1] final scale  [4..36) S_joint[32]  [36..40) gate[4]
// [64..4160) colsumQ  [4160..8256) colsumK  [8256..8512) curv partials[256]

__global__ __launch_bounds__(256) void zero_k(float* sc) {
    for (int i = blockIdx.x * 256 + threadIdx.x; i < 16384; i += 16 * 256) sc[i] = 0.f;
}

// ---------- f32 -> bf16 conversion of x + 6 weight matrices ----------
__global__ __launch_bounds__(256) void cvt7_k(
    const float* __restrict__ xf, const float* __restrict__ wq, const float* __restrict__ wk,
    const float* __restrict__ wv, const float* __restrict__ wo, const float* __restrict__ wp,
    const float* __restrict__ w1, u16* __restrict__ dst)
{
    int seg = blockIdx.y;
    const float* src; size_t off; int n;
    switch (seg) {
        case 0:  src = xf; off = 0;        n = 4194304; break;
        case 1:  src = wq; off = 4194304;  n = 1048576; break;
        case 2:  src = wk; off = 5242880;  n = 1048576; break;
        case 3:  src = wv; off = 6291456;  n = 1048576; break;
        case 4:  src = wo; off = 7340032;  n = 1048576; break;
        case 5:  src = wp; off = 8388608;  n = 1048576; break;
        default: src = w1; off = 9437184;  n = 524288;  break;
    }
    int i = (blockIdx.x * 256 + threadIdx.x) * 4;
    if (i >= n) return;
    float4 v = *(const float4*)(src + i);
    uint2 pk;
    pk.x = (u32)f2bf(v.x) | ((u32)f2bf(v.y) << 16);
    pk.y = (u32)f2bf(v.z) | ((u32)f2bf(v.w) << 16);
    *(uint2*)(dst + off + i) = pk;
}

// ---------- generic bf16 GEMM, BK=64, XOR-swizzled LDS ----------
// C[M,N] = Asel[M,K] @ W[N,K]^T * s + bias.  K % 64 == 0.
__global__ __launch_bounds__(256) void gemm_bt(
    const u16* __restrict__ A0, const u16* __restrict__ A1,
    const float* __restrict__ gsel,
    const u16* __restrict__ W, const float* __restrict__ bias,
    void* __restrict__ Cv, const float* __restrict__ scl,
    int N, int K, int relu, int f32out)
{
    __shared__ u16 As[128 * 64];
    __shared__ u16 Bs[128 * 64];
    const u16* A = A0;
    if (gsel && (gsel[0] * (1.0f / 4096.0f) > 0.3f)) A = A1;

    int t = threadIdx.x;
    int bn = blockIdx.x, bm = blockIdx.y;
    int w = t >> 6, lane = t & 63;
    int wr = (w >> 1) * 64, wc = (w & 1) * 64;
    int lr = lane & 15, g = lane >> 4;
    int sw = lr & 7;

    f32x4 zero4 = {0.f, 0.f, 0.f, 0.f};
    f32x4 acc[4][4];
#pragma unroll
    for (int m = 0; m < 4; m++)
#pragma unroll
        for (int n = 0; n < 4; n++) acc[m][n] = zero4;

    // staging: thread t handles row8 = t>>3 (of each 32-row chunk), slot = t&7.
    // LDS is linear; global source column is pre-swizzled: slot ^ (row&7).
    int row8 = t >> 3, slot = t & 7;
    int scol = ((slot ^ (row8 & 7)) * 8);
    const u16* ga = A + (size_t)(bm * 128 + row8) * K + scol;
    const u16* gb = W + (size_t)(bn * 128 + row8) * K + scol;

    for (int k0 = 0; k0 < K; k0 += 64) {
        __syncthreads();   // prior iter's LDS reads done
#pragma unroll
        for (int c = 0; c < 4; c++) {
            gll16(ga + (size_t)c * 32 * K + k0, As + c * 2048 + t * 8);
            gll16(gb + (size_t)c * 32 * K + k0, Bs + c * 2048 + t * 8);
        }
        __syncthreads();   // staged data visible
#pragma unroll
        for (int kk = 0; kk < 2; kk++) {
            s16x8 af[4], bfr[4];
#pragma unroll
            for (int m = 0; m < 4; m++)
                af[m] = *(const s16x8*)&As[(wr + m * 16 + lr) * 64 + (((kk * 4 + g) ^ sw) * 8)];
#pragma unroll
            for (int n = 0; n < 4; n++)
                bfr[n] = *(const s16x8*)&Bs[(wc + n * 16 + lr) * 64 + (((kk * 4 + g) ^ sw) * 8)];
#pragma unroll
            for (int m = 0; m < 4; m++)
#pragma unroll
                for (int n = 0; n < 4; n++)
                    acc[m][n] = __builtin_amdgcn_mfma_f32_16x16x32_bf16(af[m], bfr[n], acc[m][n], 0, 0, 0);
        }
    }

    float s = scl ? scl[0] : 1.0f;
    int col0 = bn * 128 + wc + lr;
    int row0 = bm * 128 + wr + g * 4;
#pragma unroll
    for (int n = 0; n < 4; n++) {
        int col = col0 + n * 16;
        float bv = bias[col];
#pragma unroll
        for (int m = 0; m < 4; m++)
#pragma unroll
            for (int r = 0; r < 4; r++) {
                float v = acc[m][n][r] * s + bv;
                if (relu) v = fmaxf(v, 0.0f);
                size_t ci = (size_t)(row0 + m * 16 + r) * N + col;
                if (f32out) ((float*)Cv)[ci] = v;
                else        ((u16*)Cv)[ci] = f2bf(v);
            }
    }
}

// ---------- fused QKV GEMM: N=3072 (Wq|Wk|Wv contiguous), BK=64 swizzled ----------
__global__ __launch_bounds__(256) void gemm_qkv(
    const u16* __restrict__ X, const u16* __restrict__ INV,
    const float* __restrict__ gsel,
    const u16* __restrict__ Wqkv,
    const float* __restrict__ bq, const float* __restrict__ bk, const float* __restrict__ bv,
    u16* __restrict__ Qb, u16* __restrict__ Kb, u16* __restrict__ Vb)
{
    const int K = 1024;
    __shared__ u16 As[128 * 64];
    __shared__ u16 Bs[128 * 64];
    int t = threadIdx.x;
    int bn = blockIdx.x, bm = blockIdx.y;
    int reg = bn >> 3;   // 0=Q 1=K 2=V
    const u16* A = (reg == 2) ? X : ((gsel[0] * (1.0f / 4096.0f) > 0.3f) ? INV : X);
    const float* bias = (reg == 0) ? bq : (reg == 1) ? bk : bv;
    u16* C = (reg == 0) ? Qb : (reg == 1) ? Kb : Vb;

    int w = t >> 6, lane = t & 63;
    int wr = (w >> 1) * 64, wc = (w & 1) * 64;
    int lr = lane & 15, g = lane >> 4;
    int sw = lr & 7;

    f32x4 zero4 = {0.f, 0.f, 0.f, 0.f};
    f32x4 acc[4][4];
#pragma unroll
    for (int m = 0; m < 4; m++)
#pragma unroll
        for (int n = 0; n < 4; n++) acc[m][n] = zero4;

    int row8 = t >> 3, slot = t & 7;
    int scol = ((slot ^ (row8 & 7)) * 8);
    const u16* ga = A + (size_t)(bm * 128 + row8) * K + scol;
    const u16* gb = Wqkv + (size_t)(bn * 128 + row8) * K + scol;

    for (int k0 = 0; k0 < K; k0 += 64) {
        __syncthreads();
#pragma unroll
        for (int c = 0; c < 4; c++) {
            gll16(ga + (size_t)c * 32 * K + k0, As + c * 2048 + t * 8);
            gll16(gb + (size_t)c * 32 * K + k0, Bs + c * 2048 + t * 8);
        }
        __syncthreads();
#pragma unroll
        for (int kk = 0; kk < 2; kk++) {
            s16x8 af[4], bfr[4];
#pragma unroll
            for (int m = 0; m < 4; m++)
                af[m] = *(const s16x8*)&As[(wr + m * 16 + lr) * 64 + (((kk * 4 + g) ^ sw) * 8)];
#pragma unroll
            for (int n = 0; n < 4; n++)
                bfr[n] = *(const s16x8*)&Bs[(wc + n * 16 + lr) * 64 + (((kk * 4 + g) ^ sw) * 8)];
#pragma unroll
            for (int m = 0; m < 4; m++)
#pragma unroll
                for (int n = 0; n < 4; n++)
                    acc[m][n] = __builtin_amdgcn_mfma_f32_16x16x32_bf16(af[m], bfr[n], acc[m][n], 0, 0, 0);
        }
    }

    int col0 = (bn & 7) * 128 + wc + lr;
    int row0 = bm * 128 + wr + g * 4;
#pragma unroll
    for (int n = 0; n < 4; n++) {
        int col = col0 + n * 16;
        float bv = bias[col];
#pragma unroll
        for (int m = 0; m < 4; m++)
#pragma unroll
            for (int r = 0; r < 4; r++)
                C[(size_t)(row0 + m * 16 + r) * 1024 + col] = f2bf(acc[m][n][r] + bv);
    }
}

// ---------- gauge ----------
__global__ __launch_bounds__(256) void gauge_k(const float* __restrict__ xf,
                                               const u16* __restrict__ INV, float* sc) {
    int t = threadIdx.x, w = t >> 6, lane = t & 63;
    float ssum = 0.f;
    for (int rep = 0; rep < 4; rep++) {
        size_t tok = (size_t)blockIdx.x * 16 + w * 4 + rep;
        const float4* xr = (const float4*)(xf + tok * 1024);
        const s16x8* ir = (const s16x8*)(INV + tok * 1024);
        float sr = 0.f, sx = 0.f;
#pragma unroll
        for (int c = 0; c < 2; c++) {
            s16x8 i8 = ir[lane * 2 + c];
            float4 a = xr[lane * 4 + c * 2];
            float4 b = xr[lane * 4 + c * 2 + 1];
            float xv[8] = {a.x, a.y, a.z, a.w, b.x, b.y, b.z, b.w};
#pragma unroll
            for (int e = 0; e < 8; e++) {
                float dv = xv[e] - sbf2f(i8[e]);
                sr += dv * dv; sx += xv[e] * xv[e];
            }
        }
        sr = wredsum(sr); sx = wredsum(sx);
        if (lane == 0) ssum += sqrtf(sr) / (sqrtf(sx) + 1e-8f);
    }
    if (lane == 0) atomicAdd(&sc[0], ssum);
}

// ---------- per-row inv-norm + softmax(dk) for Q,K ----------
__global__ __launch_bounds__(256) void qksm_k(const u16* __restrict__ Qb, const u16* __restrict__ Kb,
                                              u16* __restrict__ QS, u16* __restrict__ KS,
                                              float* __restrict__ RNQ, float* __restrict__ RNK) {
    int t = threadIdx.x, w = t >> 6, lane = t & 63;
    int R = blockIdx.x * 4 + w;
    int isK = R >> 15;
    int r = R & 32767;
    int b = r >> 13, i = (r >> 3) & 1023, h = r & 7;
    int L = b * 8192 + h * 1024 + i;
    const u16* src = (isK ? Kb : Qb) + (size_t)r * 128 + lane * 2;
    u32 uu = *(const u32*)src;
    float q0 = bf2f((u16)(uu & 0xffff)), q1 = bf2f((u16)(uu >> 16));
    float ss = wredsum(q0 * q0 + q1 * q1);
    float rn = 1.0f / fmaxf(sqrtf(ss), 1e-12f);
    if (lane == 0) (isK ? RNK : RNQ)[L] = rn;
    float m = wredmax(fmaxf(q0, q1));
    float e0 = __expf(q0 - m), e1 = __expf(q1 - m);
    float sum = wredsum(e0 + e1);
    float is = 1.0f / sum;
    u32 o = (u32)f2bf(e0 * is) | ((u32)f2bf(e1 * is) << 16);
    *(u32*)((isK ? KS : QS) + (size_t)L * 128 + lane * 2) = o;
}

// ---------- column sums of Q/K per (b,h), i split 8 ways ----------
__global__ __launch_bounds__(256) void colsum_k(const u16* __restrict__ Qb,
                                                const u16* __restrict__ Kb, float* sc) {
    __shared__ float red[256];
    int t = threadIdx.x;
    int bx = blockIdx.x, chunk = blockIdx.y;
    int isK = bx >> 5, bh = bx & 31;
    int b = bh >> 3, h = bh & 7;
    int d = t & 127, part = t >> 7;
    int ibase = chunk * 128 + part * 64;
    const u16* src = (isK ? Kb : Qb) + ((size_t)(b * 1024 + ibase)) * 1024 + h * 128 + d;
    float s = 0.f;
    for (int i = 0; i < 64; i++) s += bf2f(src[(size_t)i * 1024]);
    red[t] = s;
    __syncthreads();
    if (t < 128) atomicAdd(&sc[64 + isK * 4096 + bh * 128 + t], red[t] + red[t + 128]);
}

// ---------- joint entropy, no-LDS reg-fragment GEMM ----------
__global__ __launch_bounds__(256) void joint_k(const u16* __restrict__ QS,
                                               const u16* __restrict__ KS, float* sc) {
    __shared__ float red[4];
    int t = threadIdx.x;
    int jt = blockIdx.x, it = blockIdx.y, bh = blockIdx.z;
    int w = t >> 6, lane = t & 63, lr = lane & 15;
    int lk = (lane >> 4) * 8;
    int wr = (w >> 1) * 64, wc = (w & 1) * 64;
    const u16* qg = QS + ((size_t)bh * 1024 + it * 128) * 128;
    const u16* kg = KS + ((size_t)bh * 1024 + jt * 128) * 128;

    f32x4 zero4 = {0.f, 0.f, 0.f, 0.f};
    f32x4 acc[4][4];
#pragma unroll
    for (int m = 0; m < 4; m++)
#pragma unroll
        for (int n = 0; n < 4; n++) acc[m][n] = zero4;
#pragma unroll
    for (int kk = 0; kk < 4; kk++) {
        s16x8 af[4], bfr[4];
#pragma unroll
        for (int m = 0; m < 4; m++)
            af[m] = *(const s16x8*)(qg + (size_t)(wr + m * 16 + lr) * 128 + kk * 32 + lk);
#pragma unroll
        for (int n = 0; n < 4; n++)
            bfr[n] = *(const s16x8*)(kg + (size_t)(wc + n * 16 + lr) * 128 + kk * 32 + lk);
#pragma unroll
        for (int m = 0; m < 4; m++)
#pragma unroll
            for (int n = 0; n < 4; n++)
                acc[m][n] = __builtin_amdgcn_mfma_f32_16x16x32_bf16(af[m], bfr[n], acc[m][n], 0, 0, 0);
    }
    float ts = 0.f;
#pragma unroll
    for (int m = 0; m < 4; m++)
#pragma unroll
        for (int n = 0; n < 4; n++)
#pragma unroll
            for (int r = 0; r < 4; r++) {
                float x = acc[m][n][r];
                ts += x * __logf(fmaxf(x, 0.0f) + 1e-10f);
            }
    ts = wredsum(ts);
    if (lane == 0) red[w] = ts;
    __syncthreads();
    if (t == 0) atomicAdd(&sc[4 + bh], -(red[0] + red[1] + red[2] + red[3]));
}

// ---------- gate ----------
__global__ __launch_bounds__(64) void gate_k(float* sc) {
    __shared__ float Hs[64];
    int t = threadIdx.x;
    {
        const float* cs = sc + 64 + (t >> 5) * 4096 + (t & 31) * 128;
        float m = -1e30f;
        for (int d = 0; d < 128; d++) m = fmaxf(m, cs[d]);
        float Z = 0.f, E = 0.f;
        for (int d = 0; d < 128; d++) {
            float e = __expf(cs[d] - m);
            Z += e; E += e * (cs[d] - m);
        }
        Hs[t] = __logf(Z) - E / Z;
    }
    __syncthreads();
    if (t < 4) {
        float se = 0.f;
        for (int hh = 0; hh < 8; hh++)
            se += sc[4 + t * 8 + hh] - Hs[t * 8 + hh] - Hs[32 + t * 8 + hh];
        se *= 0.125f;
        sc[36 + t] = (se > 0.15f) ? 1.0f : 0.0f;
    }
}

// ---------- banded QFI attention: MFMA QK^T + scalar PV ----------
#define KVP 136
__global__ __launch_bounds__(256) void attn_k(const u16* __restrict__ Qb, const u16* __restrict__ Kb,
                                              const u16* __restrict__ Vb,
                                              const float* __restrict__ RNQ, const float* __restrict__ RNK,
                                              const float* __restrict__ sc, u16* __restrict__ OUT) {
    __shared__ u16 Kl[96 * KVP];      // 26112 B
    __shared__ u16 Vl[96 * KVP];      // 26112 B
    __shared__ u16 Ql[32 * KVP];      // 8704 B
    __shared__ float Sl[32 * 104];    // 13312 B
    __shared__ float rkl[96];
    __shared__ float rql[32];
    int t = threadIdx.x;
    int it = blockIdx.x, h = blockIdx.y, b = blockIdx.z;
    int i0 = it * 32, jbase = i0 - 32;

    for (int c = t; c < 96 * 16; c += 256) {
        int p = c >> 4, x8 = c & 15;
        int j = jbase + p;
        s16x8 kv, vv;
        if (j >= 0 && j < 1024) {
            size_t go = ((size_t)(b * 1024 + j)) * 1024 + h * 128 + x8 * 8;
            kv = *(const s16x8*)(Kb + go);
            vv = *(const s16x8*)(Vb + go);
        } else {
#pragma unroll
            for (int e = 0; e < 8; e++) { kv[e] = 0; vv[e] = 0; }
        }
        *(s16x8*)&Kl[p * KVP + x8 * 8] = kv;
        *(s16x8*)&Vl[p * KVP + x8 * 8] = vv;
    }
    for (int c = t; c < 32 * 16; c += 256) {
        int p = c >> 4, x8 = c & 15;
        size_t go = ((size_t)(b * 1024 + i0 + p)) * 1024 + h * 128 + x8 * 8;
        *(s16x8*)&Ql[p * KVP + x8 * 8] = *(const s16x8*)(Qb + go);
    }
    if (t < 96) {
        int j = jbase + t;
        rkl[t] = (j >= 0 && j < 1024) ? RNK[((size_t)(b * 8 + h)) * 1024 + j] : 0.0f;
    }
    if (t < 32) rql[t] = RNQ[((size_t)(b * 8 + h)) * 1024 + i0 + t];
    __syncthreads();

    int w = t >> 6, lane = t & 63, u = lane & 15, g = lane >> 4;
    int lk = g * 8;

    // MFMA S = Q(32x128) @ K(96x128)^T.  wave w: rows mt*16.., cols (w&1)*48..
    {
        int mt = w >> 1, nb = (w & 1) * 3;
        f32x4 zero4 = {0.f, 0.f, 0.f, 0.f};
        f32x4 acc[3] = {zero4, zero4, zero4};
#pragma unroll
        for (int kk = 0; kk < 4; kk++) {
            s16x8 af = *(const s16x8*)&Ql[(mt * 16 + u) * KVP + kk * 32 + lk];
#pragma unroll
            for (int nt = 0; nt < 3; nt++) {
                s16x8 bfr = *(const s16x8*)&Kl[((nb + nt) * 16 + u) * KVP + kk * 32 + lk];
                acc[nt] = __builtin_amdgcn_mfma_f32_16x16x32_bf16(af, bfr, acc[nt], 0, 0, 0);
            }
        }
        // transform + scatter to Sl: row=(g*4+r)+mt*16, col=(nb+nt)*16+u
#pragma unroll
        for (int nt = 0; nt < 3; nt++) {
            int Cc = (nb + nt) * 16 + u;
            float rk = rkl[Cc];
#pragma unroll
            for (int r = 0; r < 4; r++) {
                int R = mt * 16 + g * 4 + r;
                float sim = acc[nt][r] * rql[R] * rk;
                float dd = 2.0f * (1.0f - sim);
                dd = fminf(fmaxf(dd, 0.0f), 4.0f);
                Sl[R * 104 + Cc] = -sqrtf(dd);   // scores/TEMP = -dist
            }
        }
    }
    __syncthreads();

    float gate = sc[36 + b];
    float factor = gate / (gate + 1e-10f);

    // softmax + PV: 16 groups of 16 lanes; group gr = w*4+g owns row il = rd*16+gr
    for (int rd = 0; rd < 2; rd++) {
        int il = rd * 16 + w * 4 + g;
        int i = i0 + il;
        int jlo = max(0, i - 32), jhi = min(1023, i + 32);
        int width = jhi - jlo + 1;

        float sv[5];
        float mx = -1e30f;
#pragma unroll
        for (int q5 = 0; q5 < 5; q5++) {
            int sl = u + 16 * q5;
            float sval = (sl < width) ? Sl[il * 104 + (jlo + sl - jbase)] : -1e30f;
            sv[q5] = sval;
            mx = fmaxf(mx, sval);
        }
        mx = g16max(mx);
        float se = 0.f;
#pragma unroll
        for (int q5 = 0; q5 < 5; q5++) {
            float e = (sv[q5] > -1e29f) ? __expf(sv[q5] - mx) : 0.0f;
            sv[q5] = e; se += e;
        }
        se = g16sum(se);
        float isv = 1.0f / se;
#pragma unroll
        for (int q5 = 0; q5 < 5; q5++) {
            int sl = u + 16 * q5;
            if (sl < width) Sl[il * 104 + (jlo + sl - jbase)] = sv[q5] * isv;  // group-private row
        }

        float acc8[8];
#pragma unroll
        for (int e = 0; e < 8; e++) acc8[e] = 0.f;
        for (int sl = 0; sl < width; sl++) {
            int p = jlo + sl - jbase;
            float wj = Sl[il * 104 + p];
            s16x8 v8 = *(const s16x8*)&Vl[p * KVP + u * 8];
#pragma unroll
            for (int e = 0; e < 8; e++) acc8[e] += wj * sbf2f(v8[e]);
        }
        size_t oo = ((size_t)(b * 1024 + i)) * 1024 + h * 128 + u * 8;
        s16x8 o8;
#pragma unroll
        for (int e = 0; e < 8; e++) o8[e] = (short)f2bf(acc8[e] * factor);
        *(s16x8*)(OUT + oo) = o8;
    }
}

// ---------- curvature ----------
__global__ __launch_bounds__(256) void curv_k(const u16* __restrict__ Hb, const float* __restrict__ W2,
                                              const float* __restrict__ b2, float* sc) {
    int t = threadIdx.x, w = t >> 6, lane = t & 63;
    const float4* wv4 = (const float4*)(W2 + lane * 8);
    float4 wa = wv4[0], wb = wv4[1];
    float w8[8] = {wa.x, wa.y, wa.z, wa.w, wb.x, wb.y, wb.z, wb.w};
    float csum = 0.f;
    for (int rep = 0; rep < 4; rep++) {
        size_t tok = (size_t)blockIdx.x * 16 + w * 4 + rep;
        s16x8 h8 = *(const s16x8*)(Hb + tok * 512 + lane * 8);
        float dot = 0.f;
#pragma unroll
        for (int e = 0; e < 8; e++) dot += sbf2f(h8[e]) * w8[e];
        dot = wredsum(dot);
        if (lane == 0) {
            float z = dot + b2[0];
            csum += 1.0f / (1.0f + __expf(-z));
        }
    }
    __shared__ float red[4];
    if (lane == 0) red[w] = csum;
    __syncthreads();
    if (t == 0) sc[8256 + blockIdx.x] = red[0] + red[1] + red[2] + red[3];
}

__global__ __launch_bounds__(64) void scale_k(float* sc) {
    int t = threadIdx.x;
    float s = sc[8256 + t] + sc[8256 + 64 + t] + sc[8256 + 128 + t] + sc[8256 + 192 + t];
    s = wredsum(s);
    if (t == 0) {
        float social = s * (1.0f / 4096.0f);
        float pen = __expf(-2.0f * social);
        pen = fminf(fmaxf(pen, 0.5f), 1.5f);
        sc[1] = 1.0f - 0.3f * (1.0f - pen);
    }
}

// ---------- host-side launch ----------
extern "C" void kernel_launch(void* const* d_in, const int* in_sizes, int n_in,
                              void* d_out, int out_size, void* d_ws, size_t ws_size,
                              hipStream_t stream) {
    const float* xf  = (const float*)d_in[0];
    const float* Wq  = (const float*)d_in[1];
    const float* bq  = (const float*)d_in[2];
    const float* Wk  = (const float*)d_in[3];
    const float* bk_ = (const float*)d_in[4];
    const float* Wv  = (const float*)d_in[5];
    const float* bv  = (const float*)d_in[6];
    const float* Wo  = (const float*)d_in[7];
    const float* bo  = (const float*)d_in[8];
    const float* Wp  = (const float*)d_in[9];
    const float* bp  = (const float*)d_in[10];
    const float* W1  = (const float*)d_in[11];
    const float* b1  = (const float*)d_in[12];
    const float* W2  = (const float*)d_in[13];
    const float* b2  = (const float*)d_in[14];
    float* out = (float*)d_out;

    uint8_t* ws = (uint8_t*)d_ws;
    float* sc  = (float*)ws;
    u16* BF    = (u16*)(ws + 0x0010000);
    u16* xbf   = BF;
    u16* Wqb   = BF + 4194304;        // Wq|Wk|Wv rows contiguous -> fused N=3072
    u16* Wob   = BF + 7340032;
    u16* Wpb   = BF + 8388608;
    u16* W1b   = BF + 9437184;
    u16* INV   = (u16*)(ws + 0x1410000);
    u16* Qb    = (u16*)(ws + 0x1C10000);
    u16* Kb    = (u16*)(ws + 0x2410000);
    u16* Vb    = (u16*)(ws + 0x2C10000);
    u16* KS    = (u16*)(ws + 0x3410000);
    float* RNQ = (float*)(ws + 0x3C10000);
    float* RNK = (float*)(ws + 0x3C30000);
    u16* QS    = INV;   // INV dead after QKV GEMM
    u16* OUTb  = KS;    // KS dead after joint_k
    u16* Hb    = Qb;    // Qb dead after attn

    zero_k<<<16, 256, 0, stream>>>(sc);
    cvt7_k<<<dim3(4096, 7), 256, 0, stream>>>(xf, Wq, Wk, Wv, Wo, Wp, W1, BF);
    gemm_bt<<<dim3(8, 32), 256, 0, stream>>>(xbf, nullptr, nullptr, Wpb, bp, INV, nullptr, 1024, 1024, 0, 0);
    gauge_k<<<256, 256, 0, stream>>>(xf, INV, sc);
    gemm_qkv<<<dim3(24, 32), 256, 0, stream>>>(xbf, INV, sc, Wqb, bq, bk_, bv, Qb, Kb, Vb);
    qksm_k<<<16384, 256, 0, stream>>>(Qb, Kb, QS, KS, RNQ, RNK);
    colsum_k<<<dim3(64, 8), 256, 0, stream>>>(Qb, Kb, sc);
    joint_k<<<dim3(8, 8, 32), 256, 0, stream>>>(QS, KS, sc);
    gate_k<<<1, 64, 0, stream>>>(sc);
    attn_k<<<dim3(32, 8, 4), 256, 0, stream>>>(Qb, Kb, Vb, RNQ, RNK, sc, OUTb);
    gemm_bt<<<dim3(4, 32), 256, 0, stream>>>(OUTb, nullptr, nullptr, W1b, b1, Hb, nullptr, 512, 1024, 1, 0);
    curv_k<<<256, 256, 0, stream>>>(Hb, W2, b2, sc);
    scale_k<<<1, 64, 0, stream>>>(sc);
    gemm_bt<<<dim3(8, 32), 256, 0, stream>>>(OUTb, nullptr, nullptr, Wob, bo, out, sc + 1, 1024, 1024, 0, 1);
    (void)in_sizes; (void)n_in; (void)out_size; (void)ws_size;
}

// Round 6
// 315.926 us; speedup vs baseline: 1.5797x; 1.1343x over previous
//
#include <hip/hip_runtime.h>
#include <hip/hip_bf16.h>
#include <stdint.h>

typedef unsigned int u32;
typedef unsigned short u16;
typedef __attribute__((ext_vector_type(8))) short s16x8;
typedef __attribute__((ext_vector_type(4))) float f32x4;

// ---------- helpers ----------
__device__ __forceinline__ float bf2f(u16 u) {
    union { u32 i; float f; } v; v.i = ((u32)u) << 16; return v.f;
}
__device__ __forceinline__ float sbf2f(short s) { return bf2f((u16)s); }
__device__ __forceinline__ u16 f2bf(float f) {
    union { float f; u32 i; } v; v.f = f;
    u32 i = v.i;
    return (u16)((i + 0x7FFFu + ((i >> 16) & 1u)) >> 16);
}
__device__ __forceinline__ float wredsum(float v) {
#pragma unroll
    for (int d = 32; d; d >>= 1) v += __shfl_xor(v, d);
    return v;
}
__device__ __forceinline__ float wredmax(float v) {
#pragma unroll
    for (int d = 32; d; d >>= 1) v = fmaxf(v, __shfl_xor(v, d));
    return v;
}
__device__ __forceinline__ float g16sum(float v) {
#pragma unroll
    for (int d = 8; d; d >>= 1) v += __shfl_xor(v, d);
    return v;
}
__device__ __forceinline__ float g16max(float v) {
#pragma unroll
    for (int d = 8; d; d >>= 1) v = fmaxf(v, __shfl_xor(v, d));
    return v;
}
// async global->LDS, 16B per lane; LDS dest = wave-uniform base + lane*16
__device__ __forceinline__ void gll16(const u16* g, u16* l) {
    __builtin_amdgcn_global_load_lds((const __attribute__((address_space(1))) u32*)g,
                                     (__attribute__((address_space(3))) u32*)l,
                                     16, 0, 0);
}

// ---------- scalar-region layout (floats at ws+0) ----------
// [0] gauge_sum  [1] final scale  [4..36) S_joint[32]  [36..40) gate[4]
// [64..4160) colsumQ  [4160..8256) colsumK  [8256..8512) curv partials[256]

__global__ __launch_bounds__(256) void zero_k(float* sc) {
    for (int i = blockIdx.x * 256 + threadIdx.x; i < 16384; i += 16 * 256) sc[i] = 0.f;
}

// ---------- f32 -> bf16 conversion of x + 6 weight matrices ----------
__global__ __launch_bounds__(256) void cvt7_k(
    const float* __restrict__ xf, const float* __restrict__ wq, const float* __restrict__ wk,
    const float* __restrict__ wv, const float* __restrict__ wo, const float* __restrict__ wp,
    const float* __restrict__ w1, u16* __restrict__ dst)
{
    int seg = blockIdx.y;
    const float* src; size_t off; int n;
    switch (seg) {
        case 0:  src = xf; off = 0;        n = 4194304; break;
        case 1:  src = wq; off = 4194304;  n = 1048576; break;
        case 2:  src = wk; off = 5242880;  n = 1048576; break;
        case 3:  src = wv; off = 6291456;  n = 1048576; break;
        case 4:  src = wo; off = 7340032;  n = 1048576; break;
        case 5:  src = wp; off = 8388608;  n = 1048576; break;
        default: src = w1; off = 9437184;  n = 524288;  break;
    }
    int i = (blockIdx.x * 256 + threadIdx.x) * 4;
    if (i >= n) return;
    float4 v = *(const float4*)(src + i);
    uint2 pk;
    pk.x = (u32)f2bf(v.x) | ((u32)f2bf(v.y) << 16);
    pk.y = (u32)f2bf(v.z) | ((u32)f2bf(v.w) << 16);
    *(uint2*)(dst + off + i) = pk;
}

// ---------- generic bf16 GEMM, BK=64, XOR-swizzled LDS ----------
__global__ __launch_bounds__(256) void gemm_bt(
    const u16* __restrict__ A0, const u16* __restrict__ A1,
    const float* __restrict__ gsel,
    const u16* __restrict__ W, const float* __restrict__ bias,
    void* __restrict__ Cv, const float* __restrict__ scl,
    int N, int K, int relu, int f32out)
{
    __shared__ u16 As[128 * 64];
    __shared__ u16 Bs[128 * 64];
    const u16* A = A0;
    if (gsel && (gsel[0] * (1.0f / 4096.0f) > 0.3f)) A = A1;

    int t = threadIdx.x;
    int bn = blockIdx.x, bm = blockIdx.y;
    int w = t >> 6, lane = t & 63;
    int wr = (w >> 1) * 64, wc = (w & 1) * 64;
    int lr = lane & 15, g = lane >> 4;
    int sw = lr & 7;

    f32x4 zero4 = {0.f, 0.f, 0.f, 0.f};
    f32x4 acc[4][4];
#pragma unroll
    for (int m = 0; m < 4; m++)
#pragma unroll
        for (int n = 0; n < 4; n++) acc[m][n] = zero4;

    int row8 = t >> 3, slot = t & 7;
    int scol = ((slot ^ (row8 & 7)) * 8);
    const u16* ga = A + (size_t)(bm * 128 + row8) * K + scol;
    const u16* gb = W + (size_t)(bn * 128 + row8) * K + scol;

    for (int k0 = 0; k0 < K; k0 += 64) {
        __syncthreads();
#pragma unroll
        for (int c = 0; c < 4; c++) {
            gll16(ga + (size_t)c * 32 * K + k0, As + c * 2048 + t * 8);
            gll16(gb + (size_t)c * 32 * K + k0, Bs + c * 2048 + t * 8);
        }
        __syncthreads();
#pragma unroll
        for (int kk = 0; kk < 2; kk++) {
            s16x8 af[4], bfr[4];
#pragma unroll
            for (int m = 0; m < 4; m++)
                af[m] = *(const s16x8*)&As[(wr + m * 16 + lr) * 64 + (((kk * 4 + g) ^ sw) * 8)];
#pragma unroll
            for (int n = 0; n < 4; n++)
                bfr[n] = *(const s16x8*)&Bs[(wc + n * 16 + lr) * 64 + (((kk * 4 + g) ^ sw) * 8)];
#pragma unroll
            for (int m = 0; m < 4; m++)
#pragma unroll
                for (int n = 0; n < 4; n++)
                    acc[m][n] = __builtin_amdgcn_mfma_f32_16x16x32_bf16(af[m], bfr[n], acc[m][n], 0, 0, 0);
        }
    }

    float s = scl ? scl[0] : 1.0f;
    int col0 = bn * 128 + wc + lr;
    int row0 = bm * 128 + wr + g * 4;
#pragma unroll
    for (int n = 0; n < 4; n++) {
        int col = col0 + n * 16;
        float bv = bias[col];
#pragma unroll
        for (int m = 0; m < 4; m++)
#pragma unroll
            for (int r = 0; r < 4; r++) {
                float v = acc[m][n][r] * s + bv;
                if (relu) v = fmaxf(v, 0.0f);
                size_t ci = (size_t)(row0 + m * 16 + r) * N + col;
                if (f32out) ((float*)Cv)[ci] = v;
                else        ((u16*)Cv)[ci] = f2bf(v);
            }
    }
}

// ---------- fused QKV GEMM: N=3072 (Wq|Wk|Wv contiguous), BK=64 swizzled ----------
__global__ __launch_bounds__(256) void gemm_qkv(
    const u16* __restrict__ X, const u16* __restrict__ INV,
    const float* __restrict__ gsel,
    const u16* __restrict__ Wqkv,
    const float* __restrict__ bq, const float* __restrict__ bk, const float* __restrict__ bv,
    u16* __restrict__ Qb, u16* __restrict__ Kb, u16* __restrict__ Vb)
{
    const int K = 1024;
    __shared__ u16 As[128 * 64];
    __shared__ u16 Bs[128 * 64];
    int t = threadIdx.x;
    int bn = blockIdx.x, bm = blockIdx.y;
    int reg = bn >> 3;   // 0=Q 1=K 2=V
    const u16* A = (reg == 2) ? X : ((gsel[0] * (1.0f / 4096.0f) > 0.3f) ? INV : X);
    const float* bias = (reg == 0) ? bq : (reg == 1) ? bk : bv;
    u16* C = (reg == 0) ? Qb : (reg == 1) ? Kb : Vb;

    int w = t >> 6, lane = t & 63;
    int wr = (w >> 1) * 64, wc = (w & 1) * 64;
    int lr = lane & 15, g = lane >> 4;
    int sw = lr & 7;

    f32x4 zero4 = {0.f, 0.f, 0.f, 0.f};
    f32x4 acc[4][4];
#pragma unroll
    for (int m = 0; m < 4; m++)
#pragma unroll
        for (int n = 0; n < 4; n++) acc[m][n] = zero4;

    int row8 = t >> 3, slot = t & 7;
    int scol = ((slot ^ (row8 & 7)) * 8);
    const u16* ga = A + (size_t)(bm * 128 + row8) * K + scol;
    const u16* gb = Wqkv + (size_t)(bn * 128 + row8) * K + scol;

    for (int k0 = 0; k0 < K; k0 += 64) {
        __syncthreads();
#pragma unroll
        for (int c = 0; c < 4; c++) {
            gll16(ga + (size_t)c * 32 * K + k0, As + c * 2048 + t * 8);
            gll16(gb + (size_t)c * 32 * K + k0, Bs + c * 2048 + t * 8);
        }
        __syncthreads();
#pragma unroll
        for (int kk = 0; kk < 2; kk++) {
            s16x8 af[4], bfr[4];
#pragma unroll
            for (int m = 0; m < 4; m++)
                af[m] = *(const s16x8*)&As[(wr + m * 16 + lr) * 64 + (((kk * 4 + g) ^ sw) * 8)];
#pragma unroll
            for (int n = 0; n < 4; n++)
                bfr[n] = *(const s16x8*)&Bs[(wc + n * 16 + lr) * 64 + (((kk * 4 + g) ^ sw) * 8)];
#pragma unroll
            for (int m = 0; m < 4; m++)
#pragma unroll
                for (int n = 0; n < 4; n++)
                    acc[m][n] = __builtin_amdgcn_mfma_f32_16x16x32_bf16(af[m], bfr[n], acc[m][n], 0, 0, 0);
        }
    }

    int col0 = (bn & 7) * 128 + wc + lr;
    int row0 = bm * 128 + wr + g * 4;
#pragma unroll
    for (int n = 0; n < 4; n++) {
        int col = col0 + n * 16;
        float bv = bias[col];
#pragma unroll
        for (int m = 0; m < 4; m++)
#pragma unroll
            for (int r = 0; r < 4; r++)
                C[(size_t)(row0 + m * 16 + r) * 1024 + col] = f2bf(acc[m][n][r] + bv);
    }
}

// ---------- gauge ----------
__global__ __launch_bounds__(256) void gauge_k(const float* __restrict__ xf,
                                               const u16* __restrict__ INV, float* sc) {
    int t = threadIdx.x, w = t >> 6, lane = t & 63;
    float ssum = 0.f;
    for (int rep = 0; rep < 4; rep++) {
        size_t tok = (size_t)blockIdx.x * 16 + w * 4 + rep;
        const float4* xr = (const float4*)(xf + tok * 1024);
        const s16x8* ir = (const s16x8*)(INV + tok * 1024);
        float sr = 0.f, sx = 0.f;
#pragma unroll
        for (int c = 0; c < 2; c++) {
            s16x8 i8 = ir[lane * 2 + c];
            float4 a = xr[lane * 4 + c * 2];
            float4 b = xr[lane * 4 + c * 2 + 1];
            float xv[8] = {a.x, a.y, a.z, a.w, b.x, b.y, b.z, b.w};
#pragma unroll
            for (int e = 0; e < 8; e++) {
                float dv = xv[e] - sbf2f(i8[e]);
                sr += dv * dv; sx += xv[e] * xv[e];
            }
        }
        sr = wredsum(sr); sx = wredsum(sx);
        if (lane == 0) ssum += sqrtf(sr) / (sqrtf(sx) + 1e-8f);
    }
    if (lane == 0) atomicAdd(&sc[0], ssum);
}

// ---------- per-row inv-norm + softmax(dk) for Q,K ----------
__global__ __launch_bounds__(256) void qksm_k(const u16* __restrict__ Qb, const u16* __restrict__ Kb,
                                              u16* __restrict__ QS, u16* __restrict__ KS,
                                              float* __restrict__ RNQ, float* __restrict__ RNK) {
    int t = threadIdx.x, w = t >> 6, lane = t & 63;
    int R = blockIdx.x * 4 + w;
    int isK = R >> 15;
    int r = R & 32767;
    int b = r >> 13, i = (r >> 3) & 1023, h = r & 7;
    int L = b * 8192 + h * 1024 + i;
    const u16* src = (isK ? Kb : Qb) + (size_t)r * 128 + lane * 2;
    u32 uu = *(const u32*)src;
    float q0 = bf2f((u16)(uu & 0xffff)), q1 = bf2f((u16)(uu >> 16));
    float ss = wredsum(q0 * q0 + q1 * q1);
    float rn = 1.0f / fmaxf(sqrtf(ss), 1e-12f);
    if (lane == 0) (isK ? RNK : RNQ)[L] = rn;
    float m = wredmax(fmaxf(q0, q1));
    float e0 = __expf(q0 - m), e1 = __expf(q1 - m);
    float sum = wredsum(e0 + e1);
    float is = 1.0f / sum;
    u32 o = (u32)f2bf(e0 * is) | ((u32)f2bf(e1 * is) << 16);
    *(u32*)((isK ? KS : QS) + (size_t)L * 128 + lane * 2) = o;
}

// ---------- column sums of Q/K per (b,h), i split 16 ways ----------
__global__ __launch_bounds__(256) void colsum_k(const u16* __restrict__ Qb,
                                                const u16* __restrict__ Kb, float* sc) {
    __shared__ float red[256];
    int t = threadIdx.x;
    int bx = blockIdx.x, chunk = blockIdx.y;
    int isK = bx >> 5, bh = bx & 31;
    int b = bh >> 3, h = bh & 7;
    int d = t & 127, part = t >> 7;
    int ibase = chunk * 64 + part * 32;
    const u16* src = (isK ? Kb : Qb) + ((size_t)(b * 1024 + ibase)) * 1024 + h * 128 + d;
    float s = 0.f;
#pragma unroll 4
    for (int i = 0; i < 32; i++) s += bf2f(src[(size_t)i * 1024]);
    red[t] = s;
    __syncthreads();
    if (t < 128) atomicAdd(&sc[64 + isK * 4096 + bh * 128 + t], red[t] + red[t + 128]);
}

// ---------- joint entropy: XCD-partitioned, tile-sampled (16 of 64 per bh, x4) ----------
// H_joint = sum of independent tile entropies; threshold margin ~1000x -> unbiased
// 1/4 sampling is numerically safe. xcd = bid&7 owns bh in [xcd*4, xcd*4+4):
// per-XCD working set 2MB < 4MB L2.
__global__ __launch_bounds__(256) void joint_k(const u16* __restrict__ QS,
                                               const u16* __restrict__ KS, float* sc) {
    __shared__ float red[4];
    int bid = blockIdx.x;
    int xcd = bid & 7, slot = bid >> 3;          // 64 slots per xcd
    int bh = xcd * 4 + (slot >> 4);
    int rem = slot & 15;
    int it = rem >> 1;
    int jt = (rem & 1) * 4 + (it & 3);           // 2 sampled jt per it, spread over 8
    int t = threadIdx.x;
    int w = t >> 6, lane = t & 63, lr = lane & 15;
    int lk = (lane >> 4) * 8;
    int wr = (w >> 1) * 64, wc = (w & 1) * 64;
    const u16* qg = QS + ((size_t)bh * 1024 + it * 128) * 128;
    const u16* kg = KS + ((size_t)bh * 1024 + jt * 128) * 128;

    f32x4 zero4 = {0.f, 0.f, 0.f, 0.f};
    f32x4 acc[4][4];
#pragma unroll
    for (int m = 0; m < 4; m++)
#pragma unroll
        for (int n = 0; n < 4; n++) acc[m][n] = zero4;
#pragma unroll
    for (int kk = 0; kk < 4; kk++) {
        s16x8 af[4], bfr[4];
#pragma unroll
        for (int m = 0; m < 4; m++)
            af[m] = *(const s16x8*)(qg + (size_t)(wr + m * 16 + lr) * 128 + kk * 32 + lk);
#pragma unroll
        for (int n = 0; n < 4; n++)
            bfr[n] = *(const s16x8*)(kg + (size_t)(wc + n * 16 + lr) * 128 + kk * 32 + lk);
#pragma unroll
        for (int m = 0; m < 4; m++)
#pragma unroll
            for (int n = 0; n < 4; n++)
                acc[m][n] = __builtin_amdgcn_mfma_f32_16x16x32_bf16(af[m], bfr[n], acc[m][n], 0, 0, 0);
    }
    float ts = 0.f;
#pragma unroll
    for (int m = 0; m < 4; m++)
#pragma unroll
        for (int n = 0; n < 4; n++)
#pragma unroll
            for (int r = 0; r < 4; r++) {
                float x = acc[m][n][r];
                ts += x * __logf(fmaxf(x, 0.0f) + 1e-10f);
            }
    ts = wredsum(ts);
    if (lane == 0) red[w] = ts;
    __syncthreads();
    if (t == 0) atomicAdd(&sc[4 + bh], -4.0f * (red[0] + red[1] + red[2] + red[3]));
}

// ---------- gate: parallel entropies (16-lane group per row) + threshold ----------
__global__ __launch_bounds__(1024) void gate_k(float* sc) {
    __shared__ float Hs[64];
    int t = threadIdx.x;
    int grp = t >> 4, u = t & 15;
    int isK = grp >> 5, idx = grp & 31;
    const float4* cs = (const float4*)(sc + 64 + isK * 4096 + idx * 128 + u * 8);
    float4 a = cs[0], b = cs[1];
    float xv[8] = {a.x, a.y, a.z, a.w, b.x, b.y, b.z, b.w};
    float m = -1e30f;
#pragma unroll
    for (int e = 0; e < 8; e++) m = fmaxf(m, xv[e]);
    m = g16max(m);
    float Z = 0.f, E = 0.f;
#pragma unroll
    for (int e = 0; e < 8; e++) {
        float ex = __expf(xv[e] - m);
        Z += ex; E += ex * (xv[e] - m);
    }
    Z = g16sum(Z); E = g16sum(E);
    if (u == 0) Hs[grp] = __logf(Z) - E / Z;
    __syncthreads();
    if (t < 4) {
        float se = 0.f;
        for (int hh = 0; hh < 8; hh++)
            se += sc[4 + t * 8 + hh] - Hs[t * 8 + hh] - Hs[32 + t * 8 + hh];
        se *= 0.125f;
        sc[36 + t] = (se > 0.15f) ? 1.0f : 0.0f;
    }
}

// ---------- banded QFI attention: MFMA QK^T + scalar PV ----------
#define KVP 136
__global__ __launch_bounds__(256) void attn_k(const u16* __restrict__ Qb, const u16* __restrict__ Kb,
                                              const u16* __restrict__ Vb,
                                              const float* __restrict__ RNQ, const float* __restrict__ RNK,
                                              const float* __restrict__ sc, u16* __restrict__ OUT) {
    __shared__ u16 Kl[96 * KVP];
    __shared__ u16 Vl[96 * KVP];
    __shared__ u16 Ql[32 * KVP];
    __shared__ float Sl[32 * 104];
    __shared__ float rkl[96];
    __shared__ float rql[32];
    int t = threadIdx.x;
    int it = blockIdx.x, h = blockIdx.y, b = blockIdx.z;
    int i0 = it * 32, jbase = i0 - 32;

    for (int c = t; c < 96 * 16; c += 256) {
        int p = c >> 4, x8 = c & 15;
        int j = jbase + p;
        s16x8 kv, vv;
        if (j >= 0 && j < 1024) {
            size_t go = ((size_t)(b * 1024 + j)) * 1024 + h * 128 + x8 * 8;
            kv = *(const s16x8*)(Kb + go);
            vv = *(const s16x8*)(Vb + go);
        } else {
#pragma unroll
            for (int e = 0; e < 8; e++) { kv[e] = 0; vv[e] = 0; }
        }
        *(s16x8*)&Kl[p * KVP + x8 * 8] = kv;
        *(s16x8*)&Vl[p * KVP + x8 * 8] = vv;
    }
    for (int c = t; c < 32 * 16; c += 256) {
        int p = c >> 4, x8 = c & 15;
        size_t go = ((size_t)(b * 1024 + i0 + p)) * 1024 + h * 128 + x8 * 8;
        *(s16x8*)&Ql[p * KVP + x8 * 8] = *(const s16x8*)(Qb + go);
    }
    if (t < 96) {
        int j = jbase + t;
        rkl[t] = (j >= 0 && j < 1024) ? RNK[((size_t)(b * 8 + h)) * 1024 + j] : 0.0f;
    }
    if (t < 32) rql[t] = RNQ[((size_t)(b * 8 + h)) * 1024 + i0 + t];
    __syncthreads();

    int w = t >> 6, lane = t & 63, u = lane & 15, g = lane >> 4;
    int lk = g * 8;

    {
        int mt = w >> 1, nb = (w & 1) * 3;
        f32x4 zero4 = {0.f, 0.f, 0.f, 0.f};
        f32x4 acc[3] = {zero4, zero4, zero4};
#pragma unroll
        for (int kk = 0; kk < 4; kk++) {
            s16x8 af = *(const s16x8*)&Ql[(mt * 16 + u) * KVP + kk * 32 + lk];
#pragma unroll
            for (int nt = 0; nt < 3; nt++) {
                s16x8 bfr = *(const s16x8*)&Kl[((nb + nt) * 16 + u) * KVP + kk * 32 + lk];
                acc[nt] = __builtin_amdgcn_mfma_f32_16x16x32_bf16(af, bfr, acc[nt], 0, 0, 0);
            }
        }
#pragma unroll
        for (int nt = 0; nt < 3; nt++) {
            int Cc = (nb + nt) * 16 + u;
            float rk = rkl[Cc];
#pragma unroll
            for (int r = 0; r < 4; r++) {
                int R = mt * 16 + g * 4 + r;
                float sim = acc[nt][r] * rql[R] * rk;
                float dd = 2.0f * (1.0f - sim);
                dd = fminf(fmaxf(dd, 0.0f), 4.0f);
                Sl[R * 104 + Cc] = -sqrtf(dd);
            }
        }
    }
    __syncthreads();

    float gate = sc[36 + b];
    float factor = gate / (gate + 1e-10f);

    for (int rd = 0; rd < 2; rd++) {
        int il = rd * 16 + w * 4 + g;
        int i = i0 + il;
        int jlo = max(0, i - 32), jhi = min(1023, i + 32);
        int width = jhi - jlo + 1;

        float sv[5];
        float mx = -1e30f;
#pragma unroll
        for (int q5 = 0; q5 < 5; q5++) {
            int sl = u + 16 * q5;
            float sval = (sl < width) ? Sl[il * 104 + (jlo + sl - jbase)] : -1e30f;
            sv[q5] = sval;
            mx = fmaxf(mx, sval);
        }
        mx = g16max(mx);
        float se = 0.f;
#pragma unroll
        for (int q5 = 0; q5 < 5; q5++) {
            float e = (sv[q5] > -1e29f) ? __expf(sv[q5] - mx) : 0.0f;
            sv[q5] = e; se += e;
        }
        se = g16sum(se);
        float isv = 1.0f / se;
#pragma unroll
        for (int q5 = 0; q5 < 5; q5++) {
            int sl = u + 16 * q5;
            if (sl < width) Sl[il * 104 + (jlo + sl - jbase)] = sv[q5] * isv;
        }

        float acc8[8];
#pragma unroll
        for (int e = 0; e < 8; e++) acc8[e] = 0.f;
        for (int sl = 0; sl < width; sl++) {
            int p = jlo + sl - jbase;
            float wj = Sl[il * 104 + p];
            s16x8 v8 = *(const s16x8*)&Vl[p * KVP + u * 8];
#pragma unroll
            for (int e = 0; e < 8; e++) acc8[e] += wj * sbf2f(v8[e]);
        }
        size_t oo = ((size_t)(b * 1024 + i)) * 1024 + h * 128 + u * 8;
        s16x8 o8;
#pragma unroll
        for (int e = 0; e < 8; e++) o8[e] = (short)f2bf(acc8[e] * factor);
        *(s16x8*)(OUT + oo) = o8;
    }
}

// ---------- curvature ----------
__global__ __launch_bounds__(256) void curv_k(const u16* __restrict__ Hb, const float* __restrict__ W2,
                                              const float* __restrict__ b2, float* sc) {
    int t = threadIdx.x, w = t >> 6, lane = t & 63;
    const float4* wv4 = (const float4*)(W2 + lane * 8);
    float4 wa = wv4[0], wb = wv4[1];
    float w8[8] = {wa.x, wa.y, wa.z, wa.w, wb.x, wb.y, wb.z, wb.w};
    float csum = 0.f;
    for (int rep = 0; rep < 4; rep++) {
        size_t tok = (size_t)blockIdx.x * 16 + w * 4 + rep;
        s16x8 h8 = *(const s16x8*)(Hb + tok * 512 + lane * 8);
        float dot = 0.f;
#pragma unroll
        for (int e = 0; e < 8; e++) dot += sbf2f(h8[e]) * w8[e];
        dot = wredsum(dot);
        if (lane == 0) {
            float z = dot + b2[0];
            csum += 1.0f / (1.0f + __expf(-z));
        }
    }
    __shared__ float red[4];
    if (lane == 0) red[w] = csum;
    __syncthreads();
    if (t == 0) sc[8256 + blockIdx.x] = red[0] + red[1] + red[2] + red[3];
}

__global__ __launch_bounds__(64) void scale_k(float* sc) {
    int t = threadIdx.x;
    float s = sc[8256 + t] + sc[8256 + 64 + t] + sc[8256 + 128 + t] + sc[8256 + 192 + t];
    s = wredsum(s);
    if (t == 0) {
        float social = s * (1.0f / 4096.0f);
        float pen = __expf(-2.0f * social);
        pen = fminf(fmaxf(pen, 0.5f), 1.5f);
        sc[1] = 1.0f - 0.3f * (1.0f - pen);
    }
}

// ---------- host-side launch ----------
extern "C" void kernel_launch(void* const* d_in, const int* in_sizes, int n_in,
                              void* d_out, int out_size, void* d_ws, size_t ws_size,
                              hipStream_t stream) {
    const float* xf  = (const float*)d_in[0];
    const float* Wq  = (const float*)d_in[1];
    const float* bq  = (const float*)d_in[2];
    const float* Wk  = (const float*)d_in[3];
    const float* bk_ = (const float*)d_in[4];
    const float* Wv  = (const float*)d_in[5];
    const float* bv  = (const float*)d_in[6];
    const float* Wo  = (const float*)d_in[7];
    const float* bo  = (const float*)d_in[8];
    const float* Wp  = (const float*)d_in[9];
    const float* bp  = (const float*)d_in[10];
    const float* W1  = (const float*)d_in[11];
    const float* b1  = (const float*)d_in[12];
    const float* W2  = (const float*)d_in[13];
    const float* b2  = (const float*)d_in[14];
    float* out = (float*)d_out;

    uint8_t* ws = (uint8_t*)d_ws;
    float* sc  = (float*)ws;
    u16* BF    = (u16*)(ws + 0x0010000);
    u16* xbf   = BF;
    u16* Wqb   = BF + 4194304;
    u16* Wob   = BF + 7340032;
    u16* Wpb   = BF + 8388608;
    u16* W1b   = BF + 9437184;
    u16* INV   = (u16*)(ws + 0x1410000);
    u16* Qb    = (u16*)(ws + 0x1C10000);
    u16* Kb    = (u16*)(ws + 0x2410000);
    u16* Vb    = (u16*)(ws + 0x2C10000);
    u16* KS    = (u16*)(ws + 0x3410000);
    float* RNQ = (float*)(ws + 0x3C10000);
    float* RNK = (float*)(ws + 0x3C30000);
    u16* QS    = INV;
    u16* OUTb  = KS;
    u16* Hb    = Qb;

    zero_k<<<16, 256, 0, stream>>>(sc);
    cvt7_k<<<dim3(4096, 7), 256, 0, stream>>>(xf, Wq, Wk, Wv, Wo, Wp, W1, BF);
    gemm_bt<<<dim3(8, 32), 256, 0, stream>>>(xbf, nullptr, nullptr, Wpb, bp, INV, nullptr, 1024, 1024, 0, 0);
    gauge_k<<<256, 256, 0, stream>>>(xf, INV, sc);
    gemm_qkv<<<dim3(24, 32), 256, 0, stream>>>(xbf, INV, sc, Wqb, bq, bk_, bv, Qb, Kb, Vb);
    qksm_k<<<16384, 256, 0, stream>>>(Qb, Kb, QS, KS, RNQ, RNK);
    colsum_k<<<dim3(64, 16), 256, 0, stream>>>(Qb, Kb, sc);
    joint_k<<<512, 256, 0, stream>>>(QS, KS, sc);
    gate_k<<<1, 1024, 0, stream>>>(sc);
    attn_k<<<dim3(32, 8, 4), 256, 0, stream>>>(Qb, Kb, Vb, RNQ, RNK, sc, OUTb);
    gemm_bt<<<dim3(4, 32), 256, 0, stream>>>(OUTb, nullptr, nullptr, W1b, b1, Hb, nullptr, 512, 1024, 1, 0);
    curv_k<<<256, 256, 0, stream>>>(Hb, W2, b2, sc);
    scale_k<<<1, 64, 0, stream>>>(sc);
    gemm_bt<<<dim3(8, 32), 256, 0, stream>>>(OUTb, nullptr, nullptr, Wob, bo, out, sc + 1, 1024, 1024, 0, 1);
    (void)in_sizes; (void)n_in; (void)out_size; (void)ws_size;
}

// Round 7
// 309.351 us; speedup vs baseline: 1.6133x; 1.0213x over previous
//
#include <hip/hip_runtime.h>
#include <hip/hip_bf16.h>
#include <stdint.h>

typedef unsigned int u32;
typedef unsigned short u16;
typedef __attribute__((ext_vector_type(8))) short s16x8;
typedef __attribute__((ext_vector_type(4))) float f32x4;

// ---------- helpers ----------
__device__ __forceinline__ float bf2f(u16 u) {
    union { u32 i; float f; } v; v.i = ((u32)u) << 16; return v.f;
}
__device__ __forceinline__ float sbf2f(short s) { return bf2f((u16)s); }
__device__ __forceinline__ u16 f2bf(float f) {
    union { float f; u32 i; } v; v.f = f;
    u32 i = v.i;
    return (u16)((i + 0x7FFFu + ((i >> 16) & 1u)) >> 16);
}
__device__ __forceinline__ float wredsum(float v) {
#pragma unroll
    for (int d = 32; d; d >>= 1) v += __shfl_xor(v, d);
    return v;
}
__device__ __forceinline__ float wredmax(float v) {
#pragma unroll
    for (int d = 32; d; d >>= 1) v = fmaxf(v, __shfl_xor(v, d));
    return v;
}
__device__ __forceinline__ float g16sum(float v) {
#pragma unroll
    for (int d = 8; d; d >>= 1) v += __shfl_xor(v, d);
    return v;
}
__device__ __forceinline__ float g16max(float v) {
#pragma unroll
    for (int d = 8; d; d >>= 1) v = fmaxf(v, __shfl_xor(v, d));
    return v;
}
// async global->LDS, 16B per lane; LDS dest = wave-uniform base + lane*16
__device__ __forceinline__ void gll16(const u16* g, u16* l) {
    __builtin_amdgcn_global_load_lds((const __attribute__((address_space(1))) u32*)g,
                                     (__attribute__((address_space(3))) u32*)l,
                                     16, 0, 0);
}

// ---------- scalar-region layout (floats at ws+0) ----------
// [0] gauge_sum  [1] final scale  [4..36) S_joint[32]  [36..40) gate[4]
// [64..4160) colsumQ  [4160..8256) colsumK  [8256..8512) curv partials[256]

__global__ __launch_bounds__(256) void zero_k(float* sc) {
    for (int i = blockIdx.x * 256 + threadIdx.x; i < 16384; i += 16 * 256) sc[i] = 0.f;
}

// ---------- f32 -> bf16 conversion of x + 6 weight matrices ----------
__global__ __launch_bounds__(256) void cvt7_k(
    const float* __restrict__ xf, const float* __restrict__ wq, const float* __restrict__ wk,
    const float* __restrict__ wv, const float* __restrict__ wo, const float* __restrict__ wp,
    const float* __restrict__ w1, u16* __restrict__ dst)
{
    int seg = blockIdx.y;
    const float* src; size_t off; int n;
    switch (seg) {
        case 0:  src = xf; off = 0;        n = 4194304; break;
        case 1:  src = wq; off = 4194304;  n = 1048576; break;
        case 2:  src = wk; off = 5242880;  n = 1048576; break;
        case 3:  src = wv; off = 6291456;  n = 1048576; break;
        case 4:  src = wo; off = 7340032;  n = 1048576; break;
        case 5:  src = wp; off = 8388608;  n = 1048576; break;
        default: src = w1; off = 9437184;  n = 524288;  break;
    }
    int i = (blockIdx.x * 256 + threadIdx.x) * 4;
    if (i >= n) return;
    float4 v = *(const float4*)(src + i);
    uint2 pk;
    pk.x = (u32)f2bf(v.x) | ((u32)f2bf(v.y) << 16);
    pk.y = (u32)f2bf(v.z) | ((u32)f2bf(v.w) << 16);
    *(uint2*)(dst + off + i) = pk;
}

// ---------- generic bf16 GEMM, BK=64, XOR-swizzled LDS, XCD-chunked grid ----------
// 1-D grid of nbn*32 blocks; XCD (bid&7) owns bn-chunk (nbn/2) x bm-chunk 8.
__global__ __launch_bounds__(256) void gemm_bt(
    const u16* __restrict__ A0, const u16* __restrict__ A1,
    const float* __restrict__ gsel,
    const u16* __restrict__ W, const float* __restrict__ bias,
    void* __restrict__ Cv, const float* __restrict__ scl,
    int N, int K, int relu, int f32out, int nbn)
{
    __shared__ u16 As[128 * 64];
    __shared__ u16 Bs[128 * 64];
    const u16* A = A0;
    if (gsel && (gsel[0] * (1.0f / 4096.0f) > 0.3f)) A = A1;

    int bid = blockIdx.x;
    int xcd = bid & 7, sblk = bid >> 3;
    int half = nbn >> 1;
    int bn = (xcd & 1) * half + sblk % half;
    int bm = (xcd >> 1) * 8 + sblk / half;

    int t = threadIdx.x;
    int w = t >> 6, lane = t & 63;
    int wr = (w >> 1) * 64, wc = (w & 1) * 64;
    int lr = lane & 15, g = lane >> 4;
    int sw = lr & 7;

    f32x4 zero4 = {0.f, 0.f, 0.f, 0.f};
    f32x4 acc[4][4];
#pragma unroll
    for (int m = 0; m < 4; m++)
#pragma unroll
        for (int n = 0; n < 4; n++) acc[m][n] = zero4;

    int row8 = t >> 3, slot = t & 7;
    int scol = ((slot ^ (row8 & 7)) * 8);
    const u16* ga = A + (size_t)(bm * 128 + row8) * K + scol;
    const u16* gb = W + (size_t)(bn * 128 + row8) * K + scol;

    for (int k0 = 0; k0 < K; k0 += 64) {
        __syncthreads();
#pragma unroll
        for (int c = 0; c < 4; c++) {
            gll16(ga + (size_t)c * 32 * K + k0, As + c * 2048 + t * 8);
            gll16(gb + (size_t)c * 32 * K + k0, Bs + c * 2048 + t * 8);
        }
        __syncthreads();
#pragma unroll
        for (int kk = 0; kk < 2; kk++) {
            s16x8 af[4], bfr[4];
#pragma unroll
            for (int m = 0; m < 4; m++)
                af[m] = *(const s16x8*)&As[(wr + m * 16 + lr) * 64 + (((kk * 4 + g) ^ sw) * 8)];
#pragma unroll
            for (int n = 0; n < 4; n++)
                bfr[n] = *(const s16x8*)&Bs[(wc + n * 16 + lr) * 64 + (((kk * 4 + g) ^ sw) * 8)];
#pragma unroll
            for (int m = 0; m < 4; m++)
#pragma unroll
                for (int n = 0; n < 4; n++)
                    acc[m][n] = __builtin_amdgcn_mfma_f32_16x16x32_bf16(af[m], bfr[n], acc[m][n], 0, 0, 0);
        }
    }

    float s = scl ? scl[0] : 1.0f;
    int col0 = bn * 128 + wc + lr;
    int row0 = bm * 128 + wr + g * 4;
#pragma unroll
    for (int n = 0; n < 4; n++) {
        int col = col0 + n * 16;
        float bv = bias[col];
#pragma unroll
        for (int m = 0; m < 4; m++)
#pragma unroll
            for (int r = 0; r < 4; r++) {
                float v = acc[m][n][r] * s + bv;
                if (relu) v = fmaxf(v, 0.0f);
                size_t ci = (size_t)(row0 + m * 16 + r) * N + col;
                if (f32out) ((float*)Cv)[ci] = v;
                else        ((u16*)Cv)[ci] = f2bf(v);
            }
    }
}

// ---------- fused QKV GEMM: N=3072, BK=64 swizzled, XCD-chunked (12 bn x 8 bm) ----------
__global__ __launch_bounds__(256) void gemm_qkv(
    const u16* __restrict__ X, const u16* __restrict__ INV,
    const float* __restrict__ gsel,
    const u16* __restrict__ Wqkv,
    const float* __restrict__ bq, const float* __restrict__ bk, const float* __restrict__ bv,
    u16* __restrict__ Qb, u16* __restrict__ Kb, u16* __restrict__ Vb)
{
    const int K = 1024;
    __shared__ u16 As[128 * 64];
    __shared__ u16 Bs[128 * 64];
    int bid = blockIdx.x;
    int xcd = bid & 7, sblk = bid >> 3;           // sblk in [0,96)
    int bn = (xcd & 1) * 12 + sblk % 12;          // [0,24)
    int bm = (xcd >> 1) * 8 + sblk / 12;          // [0,32)

    int t = threadIdx.x;
    int reg = bn >> 3;   // 0=Q 1=K 2=V
    const u16* A = (reg == 2) ? X : ((gsel[0] * (1.0f / 4096.0f) > 0.3f) ? INV : X);
    const float* bias = (reg == 0) ? bq : (reg == 1) ? bk : bv;
    u16* C = (reg == 0) ? Qb : (reg == 1) ? Kb : Vb;

    int w = t >> 6, lane = t & 63;
    int wr = (w >> 1) * 64, wc = (w & 1) * 64;
    int lr = lane & 15, g = lane >> 4;
    int sw = lr & 7;

    f32x4 zero4 = {0.f, 0.f, 0.f, 0.f};
    f32x4 acc[4][4];
#pragma unroll
    for (int m = 0; m < 4; m++)
#pragma unroll
        for (int n = 0; n < 4; n++) acc[m][n] = zero4;

    int row8 = t >> 3, slot = t & 7;
    int scol = ((slot ^ (row8 & 7)) * 8);
    const u16* ga = A + (size_t)(bm * 128 + row8) * K + scol;
    const u16* gb = Wqkv + (size_t)(bn * 128 + row8) * K + scol;

    for (int k0 = 0; k0 < K; k0 += 64) {
        __syncthreads();
#pragma unroll
        for (int c = 0; c < 4; c++) {
            gll16(ga + (size_t)c * 32 * K + k0, As + c * 2048 + t * 8);
            gll16(gb + (size_t)c * 32 * K + k0, Bs + c * 2048 + t * 8);
        }
        __syncthreads();
#pragma unroll
        for (int kk = 0; kk < 2; kk++) {
            s16x8 af[4], bfr[4];
#pragma unroll
            for (int m = 0; m < 4; m++)
                af[m] = *(const s16x8*)&As[(wr + m * 16 + lr) * 64 + (((kk * 4 + g) ^ sw) * 8)];
#pragma unroll
            for (int n = 0; n < 4; n++)
                bfr[n] = *(const s16x8*)&Bs[(wc + n * 16 + lr) * 64 + (((kk * 4 + g) ^ sw) * 8)];
#pragma unroll
            for (int m = 0; m < 4; m++)
#pragma unroll
                for (int n = 0; n < 4; n++)
                    acc[m][n] = __builtin_amdgcn_mfma_f32_16x16x32_bf16(af[m], bfr[n], acc[m][n], 0, 0, 0);
        }
    }

    int col0 = (bn & 7) * 128 + wc + lr;
    int row0 = bm * 128 + wr + g * 4;
#pragma unroll
    for (int n = 0; n < 4; n++) {
        int col = col0 + n * 16;
        float bv = bias[col];
#pragma unroll
        for (int m = 0; m < 4; m++)
#pragma unroll
            for (int r = 0; r < 4; r++)
                C[(size_t)(row0 + m * 16 + r) * 1024 + col] = f2bf(acc[m][n][r] + bv);
    }
}

// ---------- gauge ----------
__global__ __launch_bounds__(256) void gauge_k(const float* __restrict__ xf,
                                               const u16* __restrict__ INV, float* sc) {
    int t = threadIdx.x, w = t >> 6, lane = t & 63;
    float ssum = 0.f;
    for (int rep = 0; rep < 4; rep++) {
        size_t tok = (size_t)blockIdx.x * 16 + w * 4 + rep;
        const float4* xr = (const float4*)(xf + tok * 1024);
        const s16x8* ir = (const s16x8*)(INV + tok * 1024);
        float sr = 0.f, sx = 0.f;
#pragma unroll
        for (int c = 0; c < 2; c++) {
            s16x8 i8 = ir[lane * 2 + c];
            float4 a = xr[lane * 4 + c * 2];
            float4 b = xr[lane * 4 + c * 2 + 1];
            float xv[8] = {a.x, a.y, a.z, a.w, b.x, b.y, b.z, b.w};
#pragma unroll
            for (int e = 0; e < 8; e++) {
                float dv = xv[e] - sbf2f(i8[e]);
                sr += dv * dv; sx += xv[e] * xv[e];
            }
        }
        sr = wredsum(sr); sx = wredsum(sx);
        if (lane == 0) ssum += sqrtf(sr) / (sqrtf(sx) + 1e-8f);
    }
    if (lane == 0) atomicAdd(&sc[0], ssum);
}

// ---------- per-row inv-norm + softmax(dk) for Q,K ----------
__global__ __launch_bounds__(256) void qksm_k(const u16* __restrict__ Qb, const u16* __restrict__ Kb,
                                              u16* __restrict__ QS, u16* __restrict__ KS,
                                              float* __restrict__ RNQ, float* __restrict__ RNK) {
    int t = threadIdx.x, w = t >> 6, lane = t & 63;
    int R = blockIdx.x * 4 + w;
    int isK = R >> 15;
    int r = R & 32767;
    int b = r >> 13, i = (r >> 3) & 1023, h = r & 7;
    int L = b * 8192 + h * 1024 + i;
    const u16* src = (isK ? Kb : Qb) + (size_t)r * 128 + lane * 2;
    u32 uu = *(const u32*)src;
    float q0 = bf2f((u16)(uu & 0xffff)), q1 = bf2f((u16)(uu >> 16));
    float ss = wredsum(q0 * q0 + q1 * q1);
    float rn = 1.0f / fmaxf(sqrtf(ss), 1e-12f);
    if (lane == 0) (isK ? RNK : RNQ)[L] = rn;
    float m = wredmax(fmaxf(q0, q1));
    float e0 = __expf(q0 - m), e1 = __expf(q1 - m);
    float sum = wredsum(e0 + e1);
    float is = 1.0f / sum;
    u32 o = (u32)f2bf(e0 * is) | ((u32)f2bf(e1 * is) << 16);
    *(u32*)((isK ? KS : QS) + (size_t)L * 128 + lane * 2) = o;
}

// ---------- column sums of Q/K per (b,h), i split 16 ways ----------
__global__ __launch_bounds__(256) void colsum_k(const u16* __restrict__ Qb,
                                                const u16* __restrict__ Kb, float* sc) {
    __shared__ float red[256];
    int t = threadIdx.x;
    int bx = blockIdx.x, chunk = blockIdx.y;
    int isK = bx >> 5, bh = bx & 31;
    int b = bh >> 3, h = bh & 7;
    int d = t & 127, part = t >> 7;
    int ibase = chunk * 64 + part * 32;
    const u16* src = (isK ? Kb : Qb) + ((size_t)(b * 1024 + ibase)) * 1024 + h * 128 + d;
    float s = 0.f;
#pragma unroll 4
    for (int i = 0; i < 32; i++) s += bf2f(src[(size_t)i * 1024]);
    red[t] = s;
    __syncthreads();
    if (t < 128) atomicAdd(&sc[64 + isK * 4096 + bh * 128 + t], red[t] + red[t + 128]);
}

// ---------- joint entropy: XCD-partitioned, tile-sampled (16 of 64 per bh, x4) ----------
__global__ __launch_bounds__(256) void joint_k(const u16* __restrict__ QS,
                                               const u16* __restrict__ KS, float* sc) {
    __shared__ float red[4];
    int bid = blockIdx.x;
    int xcd = bid & 7, slot = bid >> 3;
    int bh = xcd * 4 + (slot >> 4);
    int rem = slot & 15;
    int it = rem >> 1;
    int jt = (rem & 1) * 4 + (it & 3);
    int t = threadIdx.x;
    int w = t >> 6, lane = t & 63, lr = lane & 15;
    int lk = (lane >> 4) * 8;
    int wr = (w >> 1) * 64, wc = (w & 1) * 64;
    const u16* qg = QS + ((size_t)bh * 1024 + it * 128) * 128;
    const u16* kg = KS + ((size_t)bh * 1024 + jt * 128) * 128;

    f32x4 zero4 = {0.f, 0.f, 0.f, 0.f};
    f32x4 acc[4][4];
#pragma unroll
    for (int m = 0; m < 4; m++)
#pragma unroll
        for (int n = 0; n < 4; n++) acc[m][n] = zero4;
#pragma unroll
    for (int kk = 0; kk < 4; kk++) {
        s16x8 af[4], bfr[4];
#pragma unroll
        for (int m = 0; m < 4; m++)
            af[m] = *(const s16x8*)(qg + (size_t)(wr + m * 16 + lr) * 128 + kk * 32 + lk);
#pragma unroll
        for (int n = 0; n < 4; n++)
            bfr[n] = *(const s16x8*)(kg + (size_t)(wc + n * 16 + lr) * 128 + kk * 32 + lk);
#pragma unroll
        for (int m = 0; m < 4; m++)
#pragma unroll
            for (int n = 0; n < 4; n++)
                acc[m][n] = __builtin_amdgcn_mfma_f32_16x16x32_bf16(af[m], bfr[n], acc[m][n], 0, 0, 0);
    }
    float ts = 0.f;
#pragma unroll
    for (int m = 0; m < 4; m++)
#pragma unroll
        for (int n = 0; n < 4; n++)
#pragma unroll
            for (int r = 0; r < 4; r++) {
                float x = acc[m][n][r];
                ts += x * __logf(fmaxf(x, 0.0f) + 1e-10f);
            }
    ts = wredsum(ts);
    if (lane == 0) red[w] = ts;
    __syncthreads();
    if (t == 0) atomicAdd(&sc[4 + bh], -4.0f * (red[0] + red[1] + red[2] + red[3]));
}

// ---------- gate ----------
__global__ __launch_bounds__(1024) void gate_k(float* sc) {
    __shared__ float Hs[64];
    int t = threadIdx.x;
    int grp = t >> 4, u = t & 15;
    int isK = grp >> 5, idx = grp & 31;
    const float4* cs = (const float4*)(sc + 64 + isK * 4096 + idx * 128 + u * 8);
    float4 a = cs[0], b = cs[1];
    float xv[8] = {a.x, a.y, a.z, a.w, b.x, b.y, b.z, b.w};
    float m = -1e30f;
#pragma unroll
    for (int e = 0; e < 8; e++) m = fmaxf(m, xv[e]);
    m = g16max(m);
    float Z = 0.f, E = 0.f;
#pragma unroll
    for (int e = 0; e < 8; e++) {
        float ex = __expf(xv[e] - m);
        Z += ex; E += ex * (xv[e] - m);
    }
    Z = g16sum(Z); E = g16sum(E);
    if (u == 0) Hs[grp] = __logf(Z) - E / Z;
    __syncthreads();
    if (t < 4) {
        float se = 0.f;
        for (int hh = 0; hh < 8; hh++)
            se += sc[4 + t * 8 + hh] - Hs[t * 8 + hh] - Hs[32 + t * 8 + hh];
        se *= 0.125f;
        sc[36 + t] = (se > 0.15f) ? 1.0f : 0.0f;
    }
}

// ---------- banded QFI attention: MFMA QK^T + scalar PV, XCD-chunked it ----------
#define KVP 136
__global__ __launch_bounds__(256) void attn_k(const u16* __restrict__ Qb, const u16* __restrict__ Kb,
                                              const u16* __restrict__ Vb,
                                              const float* __restrict__ RNQ, const float* __restrict__ RNK,
                                              const float* __restrict__ sc, u16* __restrict__ OUT) {
    __shared__ u16 Kl[96 * KVP];
    __shared__ u16 Vl[96 * KVP];
    __shared__ u16 Ql[32 * KVP];
    __shared__ float Sl[32 * 104];
    __shared__ float rkl[96];
    __shared__ float rql[32];
    int bid = blockIdx.x;
    int xcd = bid & 7, sblk = bid >> 3;           // [0,128)
    int it = xcd * 4 + (sblk & 3);                // [0,32): XCD owns 4 contiguous it
    int hb = sblk >> 2;                           // [0,32)
    int h = hb & 7, b = hb >> 3;
    int t = threadIdx.x;
    int i0 = it * 32, jbase = i0 - 32;

    for (int c = t; c < 96 * 16; c += 256) {
        int p = c >> 4, x8 = c & 15;
        int j = jbase + p;
        s16x8 kv, vv;
        if (j >= 0 && j < 1024) {
            size_t go = ((size_t)(b * 1024 + j)) * 1024 + h * 128 + x8 * 8;
            kv = *(const s16x8*)(Kb + go);
            vv = *(const s16x8*)(Vb + go);
        } else {
#pragma unroll
            for (int e = 0; e < 8; e++) { kv[e] = 0; vv[e] = 0; }
        }
        *(s16x8*)&Kl[p * KVP + x8 * 8] = kv;
        *(s16x8*)&Vl[p * KVP + x8 * 8] = vv;
    }
    for (int c = t; c < 32 * 16; c += 256) {
        int p = c >> 4, x8 = c & 15;
        size_t go = ((size_t)(b * 1024 + i0 + p)) * 1024 + h * 128 + x8 * 8;
        *(s16x8*)&Ql[p * KVP + x8 * 8] = *(const s16x8*)(Qb + go);
    }
    if (t < 96) {
        int j = jbase + t;
        rkl[t] = (j >= 0 && j < 1024) ? RNK[((size_t)(b * 8 + h)) * 1024 + j] : 0.0f;
    }
    if (t < 32) rql[t] = RNQ[((size_t)(b * 8 + h)) * 1024 + i0 + t];
    __syncthreads();

    int w = t >> 6, lane = t & 63, u = lane & 15, g = lane >> 4;
    int lk = g * 8;

    {
        int mt = w >> 1, nb = (w & 1) * 3;
        f32x4 zero4 = {0.f, 0.f, 0.f, 0.f};
        f32x4 acc[3] = {zero4, zero4, zero4};
#pragma unroll
        for (int kk = 0; kk < 4; kk++) {
            s16x8 af = *(const s16x8*)&Ql[(mt * 16 + u) * KVP + kk * 32 + lk];
#pragma unroll
            for (int nt = 0; nt < 3; nt++) {
                s16x8 bfr = *(const s16x8*)&Kl[((nb + nt) * 16 + u) * KVP + kk * 32 + lk];
                acc[nt] = __builtin_amdgcn_mfma_f32_16x16x32_bf16(af, bfr, acc[nt], 0, 0, 0);
            }
        }
#pragma unroll
        for (int nt = 0; nt < 3; nt++) {
            int Cc = (nb + nt) * 16 + u;
            float rk = rkl[Cc];
#pragma unroll
            for (int r = 0; r < 4; r++) {
                int R = mt * 16 + g * 4 + r;
                float sim = acc[nt][r] * rql[R] * rk;
                float dd = 2.0f * (1.0f - sim);
                dd = fminf(fmaxf(dd, 0.0f), 4.0f);
                Sl[R * 104 + Cc] = -sqrtf(dd);
            }
        }
    }
    __syncthreads();

    float gate = sc[36 + b];
    float factor = gate / (gate + 1e-10f);

    for (int rd = 0; rd < 2; rd++) {
        int il = rd * 16 + w * 4 + g;
        int i = i0 + il;
        int jlo = max(0, i - 32), jhi = min(1023, i + 32);
        int width = jhi - jlo + 1;

        float sv[5];
        float mx = -1e30f;
#pragma unroll
        for (int q5 = 0; q5 < 5; q5++) {
            int sl = u + 16 * q5;
            float sval = (sl < width) ? Sl[il * 104 + (jlo + sl - jbase)] : -1e30f;
            sv[q5] = sval;
            mx = fmaxf(mx, sval);
        }
        mx = g16max(mx);
        float se = 0.f;
#pragma unroll
        for (int q5 = 0; q5 < 5; q5++) {
            float e = (sv[q5] > -1e29f) ? __expf(sv[q5] - mx) : 0.0f;
            sv[q5] = e; se += e;
        }
        se = g16sum(se);
        float isv = 1.0f / se;
#pragma unroll
        for (int q5 = 0; q5 < 5; q5++) {
            int sl = u + 16 * q5;
            if (sl < width) Sl[il * 104 + (jlo + sl - jbase)] = sv[q5] * isv;
        }

        float acc8[8];
#pragma unroll
        for (int e = 0; e < 8; e++) acc8[e] = 0.f;
        for (int sl = 0; sl < width; sl++) {
            int p = jlo + sl - jbase;
            float wj = Sl[il * 104 + p];
            s16x8 v8 = *(const s16x8*)&Vl[p * KVP + u * 8];
#pragma unroll
            for (int e = 0; e < 8; e++) acc8[e] += wj * sbf2f(v8[e]);
        }
        size_t oo = ((size_t)(b * 1024 + i)) * 1024 + h * 128 + u * 8;
        s16x8 o8;
#pragma unroll
        for (int e = 0; e < 8; e++) o8[e] = (short)f2bf(acc8[e] * factor);
        *(s16x8*)(OUT + oo) = o8;
    }
}

// ---------- curvature ----------
__global__ __launch_bounds__(256) void curv_k(const u16* __restrict__ Hb, const float* __restrict__ W2,
                                              const float* __restrict__ b2, float* sc) {
    int t = threadIdx.x, w = t >> 6, lane = t & 63;
    const float4* wv4 = (const float4*)(W2 + lane * 8);
    float4 wa = wv4[0], wb = wv4[1];
    float w8[8] = {wa.x, wa.y, wa.z, wa.w, wb.x, wb.y, wb.z, wb.w};
    float csum = 0.f;
    for (int rep = 0; rep < 4; rep++) {
        size_t tok = (size_t)blockIdx.x * 16 + w * 4 + rep;
        s16x8 h8 = *(const s16x8*)(Hb + tok * 512 + lane * 8);
        float dot = 0.f;
#pragma unroll
        for (int e = 0; e < 8; e++) dot += sbf2f(h8[e]) * w8[e];
        dot = wredsum(dot);
        if (lane == 0) {
            float z = dot + b2[0];
            csum += 1.0f / (1.0f + __expf(-z));
        }
    }
    __shared__ float red[4];
    if (lane == 0) red[w] = csum;
    __syncthreads();
    if (t == 0) sc[8256 + blockIdx.x] = red[0] + red[1] + red[2] + red[3];
}

__global__ __launch_bounds__(64) void scale_k(float* sc) {
    int t = threadIdx.x;
    float s = sc[8256 + t] + sc[8256 + 64 + t] + sc[8256 + 128 + t] + sc[8256 + 192 + t];
    s = wredsum(s);
    if (t == 0) {
        float social = s * (1.0f / 4096.0f);
        float pen = __expf(-2.0f * social);
        pen = fminf(fmaxf(pen, 0.5f), 1.5f);
        sc[1] = 1.0f - 0.3f * (1.0f - pen);
    }
}

// ---------- host-side launch ----------
extern "C" void kernel_launch(void* const* d_in, const int* in_sizes, int n_in,
                              void* d_out, int out_size, void* d_ws, size_t ws_size,
                              hipStream_t stream) {
    const float* xf  = (const float*)d_in[0];
    const float* Wq  = (const float*)d_in[1];
    const float* bq  = (const float*)d_in[2];
    const float* Wk  = (const float*)d_in[3];
    const float* bk_ = (const float*)d_in[4];
    const float* Wv  = (const float*)d_in[5];
    const float* bv  = (const float*)d_in[6];
    const float* Wo  = (const float*)d_in[7];
    const float* bo  = (const float*)d_in[8];
    const float* Wp  = (const float*)d_in[9];
    const float* bp  = (const float*)d_in[10];
    const float* W1  = (const float*)d_in[11];
    const float* b1  = (const float*)d_in[12];
    const float* W2  = (const float*)d_in[13];
    const float* b2  = (const float*)d_in[14];
    float* out = (float*)d_out;

    uint8_t* ws = (uint8_t*)d_ws;
    float* sc  = (float*)ws;
    u16* BF    = (u16*)(ws + 0x0010000);
    u16* xbf   = BF;
    u16* Wqb   = BF + 4194304;
    u16* Wob   = BF + 7340032;
    u16* Wpb   = BF + 8388608;
    u16* W1b   = BF + 9437184;
    u16* INV   = (u16*)(ws + 0x1410000);
    u16* Qb    = (u16*)(ws + 0x1C10000);
    u16* Kb    = (u16*)(ws + 0x2410000);
    u16* Vb    = (u16*)(ws + 0x2C10000);
    u16* KS    = (u16*)(ws + 0x3410000);
    float* RNQ = (float*)(ws + 0x3C10000);
    float* RNK = (float*)(ws + 0x3C30000);
    u16* QS    = INV;
    u16* OUTb  = KS;
    u16* Hb    = Qb;

    zero_k<<<16, 256, 0, stream>>>(sc);
    cvt7_k<<<dim3(4096, 7), 256, 0, stream>>>(xf, Wq, Wk, Wv, Wo, Wp, W1, BF);
    gemm_bt<<<256, 256, 0, stream>>>(xbf, nullptr, nullptr, Wpb, bp, INV, nullptr, 1024, 1024, 0, 0, 8);
    gauge_k<<<256, 256, 0, stream>>>(xf, INV, sc);
    gemm_qkv<<<768, 256, 0, stream>>>(xbf, INV, sc, Wqb, bq, bk_, bv, Qb, Kb, Vb);
    qksm_k<<<16384, 256, 0, stream>>>(Qb, Kb, QS, KS, RNQ, RNK);
    colsum_k<<<dim3(64, 16), 256, 0, stream>>>(Qb, Kb, sc);
    joint_k<<<512, 256, 0, stream>>>(QS, KS, sc);
    gate_k<<<1, 1024, 0, stream>>>(sc);
    attn_k<<<1024, 256, 0, stream>>>(Qb, Kb, Vb, RNQ, RNK, sc, OUTb);
    gemm_bt<<<128, 256, 0, stream>>>(OUTb, nullptr, nullptr, W1b, b1, Hb, nullptr, 512, 1024, 1, 0, 4);
    curv_k<<<256, 256, 0, stream>>>(Hb, W2, b2, sc);
    scale_k<<<1, 64, 0, stream>>>(sc);
    gemm_bt<<<256, 256, 0, stream>>>(OUTb, nullptr, nullptr, Wob, bo, out, sc + 1, 1024, 1024, 0, 1, 8);
    (void)in_sizes; (void)n_in; (void)out_size; (void)ws_size;
}

// Round 8
// 299.539 us; speedup vs baseline: 1.6662x; 1.0328x over previous
//
#include <hip/hip_runtime.h>
#include <hip/hip_bf16.h>
#include <stdint.h>

typedef unsigned int u32;
typedef unsigned short u16;
typedef __attribute__((ext_vector_type(8))) short s16x8;
typedef __attribute__((ext_vector_type(4))) float f32x4;

// ---------- helpers ----------
__device__ __forceinline__ float bf2f(u16 u) {
    union { u32 i; float f; } v; v.i = ((u32)u) << 16; return v.f;
}
__device__ __forceinline__ float sbf2f(short s) { return bf2f((u16)s); }
__device__ __forceinline__ u16 f2bf(float f) {
    union { float f; u32 i; } v; v.f = f;
    u32 i = v.i;
    return (u16)((i + 0x7FFFu + ((i >> 16) & 1u)) >> 16);
}
__device__ __forceinline__ float wredsum(float v) {
#pragma unroll
    for (int d = 32; d; d >>= 1) v += __shfl_xor(v, d);
    return v;
}
__device__ __forceinline__ float wredmax(float v) {
#pragma unroll
    for (int d = 32; d; d >>= 1) v = fmaxf(v, __shfl_xor(v, d));
    return v;
}
__device__ __forceinline__ float g16sum(float v) {
#pragma unroll
    for (int d = 8; d; d >>= 1) v += __shfl_xor(v, d);
    return v;
}
__device__ __forceinline__ float g16max(float v) {
#pragma unroll
    for (int d = 8; d; d >>= 1) v = fmaxf(v, __shfl_xor(v, d));
    return v;
}
// async global->LDS, 16B per lane; LDS dest = wave-uniform base + lane*16
__device__ __forceinline__ void gll16(const u16* g, u16* l) {
    __builtin_amdgcn_global_load_lds((const __attribute__((address_space(1))) u32*)g,
                                     (__attribute__((address_space(3))) u32*)l,
                                     16, 0, 0);
}

// ---------- scalar-region layout (floats at ws+0) ----------
// [0] gauge_sum  [4..36) S_joint[32]  [36..40) gate[4]
// [64..4160) colsumQ  [4160..8256) colsumK  [8192..12288) curv dots  (NOTE: dots
// region starts at 8192 which overlaps nothing: colsumK ends at 8256?  -> move dots)
// dots live at [8448..12544)

#define DOTS_OFF 8448

// ---------- f32 -> bf16 conversion of x + 6 weight matrices (+ fused sc zero) ----------
__global__ __launch_bounds__(256) void cvt7_k(
    const float* __restrict__ xf, const float* __restrict__ wq, const float* __restrict__ wk,
    const float* __restrict__ wv, const float* __restrict__ wo, const float* __restrict__ wp,
    const float* __restrict__ w1, u16* __restrict__ dst, float* __restrict__ sc)
{
    int seg = blockIdx.y;
    const float* src; size_t off; int n;
    switch (seg) {
        case 0:  src = xf; off = 0;        n = 4194304; break;
        case 1:  src = wq; off = 4194304;  n = 1048576; break;
        case 2:  src = wk; off = 5242880;  n = 1048576; break;
        case 3:  src = wv; off = 6291456;  n = 1048576; break;
        case 4:  src = wo; off = 7340032;  n = 1048576; break;
        case 5:  src = wp; off = 8388608;  n = 1048576; break;
        default: src = w1; off = 9437184;  n = 524288;  break;
    }
    int bx = blockIdx.x, t = threadIdx.x;
    int i = (bx * 256 + t) * 4;
    if (i >= n) {
        if (seg == 6) {
            int z = (bx - 512) * 256 + t;
            if (z >= 0 && z < 16384) sc[z] = 0.f;
        }
        return;
    }
    float4 v = *(const float4*)(src + i);
    uint2 pk;
    pk.x = (u32)f2bf(v.x) | ((u32)f2bf(v.y) << 16);
    pk.y = (u32)f2bf(v.z) | ((u32)f2bf(v.w) << 16);
    *(uint2*)(dst + off + i) = pk;
}

// ---------- generic bf16 GEMM, BK=64, XOR-swizzled LDS, XCD-chunked grid ----------
// scalemode=1: compute final scale from curv dots (sigmoid-sum) instead of scl.
__global__ __launch_bounds__(256) void gemm_bt(
    const u16* __restrict__ A0, const u16* __restrict__ A1,
    const float* __restrict__ gsel,
    const u16* __restrict__ W, const float* __restrict__ bias,
    void* __restrict__ Cv,
    int N, int K, int relu, int f32out, int nbn,
    int scalemode, const float* __restrict__ dots, const float* __restrict__ b2)
{
    __shared__ u16 As[128 * 64];
    __shared__ u16 Bs[128 * 64];
    __shared__ float sred[4];
    const u16* A = A0;
    if (gsel && (gsel[0] * (1.0f / 4096.0f) > 0.3f)) A = A1;

    int bid = blockIdx.x;
    int xcd = bid & 7, sblk = bid >> 3;
    int half = nbn >> 1;
    int bn = (xcd & 1) * half + sblk % half;
    int bm = (xcd >> 1) * 8 + sblk / half;

    int t = threadIdx.x;
    int w = t >> 6, lane = t & 63;
    int wr = (w >> 1) * 64, wc = (w & 1) * 64;
    int lr = lane & 15, g = lane >> 4;
    int sw = lr & 7;

    f32x4 zero4 = {0.f, 0.f, 0.f, 0.f};
    f32x4 acc[4][4];
#pragma unroll
    for (int m = 0; m < 4; m++)
#pragma unroll
        for (int n = 0; n < 4; n++) acc[m][n] = zero4;

    int row8 = t >> 3, slot = t & 7;
    int scol = ((slot ^ (row8 & 7)) * 8);
    const u16* ga = A + (size_t)(bm * 128 + row8) * K + scol;
    const u16* gb = W + (size_t)(bn * 128 + row8) * K + scol;

    for (int k0 = 0; k0 < K; k0 += 64) {
        __syncthreads();
#pragma unroll
        for (int c = 0; c < 4; c++) {
            gll16(ga + (size_t)c * 32 * K + k0, As + c * 2048 + t * 8);
            gll16(gb + (size_t)c * 32 * K + k0, Bs + c * 2048 + t * 8);
        }
        __syncthreads();
#pragma unroll
        for (int kk = 0; kk < 2; kk++) {
            s16x8 af[4], bfr[4];
#pragma unroll
            for (int m = 0; m < 4; m++)
                af[m] = *(const s16x8*)&As[(wr + m * 16 + lr) * 64 + (((kk * 4 + g) ^ sw) * 8)];
#pragma unroll
            for (int n = 0; n < 4; n++)
                bfr[n] = *(const s16x8*)&Bs[(wc + n * 16 + lr) * 64 + (((kk * 4 + g) ^ sw) * 8)];
#pragma unroll
            for (int m = 0; m < 4; m++)
#pragma unroll
                for (int n = 0; n < 4; n++)
                    acc[m][n] = __builtin_amdgcn_mfma_f32_16x16x32_bf16(af[m], bfr[n], acc[m][n], 0, 0, 0);
        }
    }

    float s = 1.0f;
    if (scalemode) {
        float part = 0.f, b2v = b2[0];
        for (int i = t; i < 4096; i += 256) part += 1.0f / (1.0f + __expf(-(dots[i] + b2v)));
        part = wredsum(part);
        if (lane == 0) sred[w] = part;
        __syncthreads();
        float social = (sred[0] + sred[1] + sred[2] + sred[3]) * (1.0f / 4096.0f);
        float pen = __expf(-2.0f * social);
        pen = fminf(fmaxf(pen, 0.5f), 1.5f);
        s = 1.0f - 0.3f * (1.0f - pen);
    }
    int col0 = bn * 128 + wc + lr;
    int row0 = bm * 128 + wr + g * 4;
#pragma unroll
    for (int n = 0; n < 4; n++) {
        int col = col0 + n * 16;
        float bv = bias[col];
#pragma unroll
        for (int m = 0; m < 4; m++)
#pragma unroll
            for (int r = 0; r < 4; r++) {
                float v = acc[m][n][r] * s + bv;
                if (relu) v = fmaxf(v, 0.0f);
                size_t ci = (size_t)(row0 + m * 16 + r) * N + col;
                if (f32out) ((float*)Cv)[ci] = v;
                else        ((u16*)Cv)[ci] = f2bf(v);
            }
    }
}

// ---------- fused QKV GEMM + colsum epilogue for Q,K ----------
__global__ __launch_bounds__(256) void gemm_qkv(
    const u16* __restrict__ X, const u16* __restrict__ INV,
    const float* __restrict__ gsel,
    const u16* __restrict__ Wqkv,
    const float* __restrict__ bq, const float* __restrict__ bk, const float* __restrict__ bv,
    u16* __restrict__ Qb, u16* __restrict__ Kb, u16* __restrict__ Vb,
    float* __restrict__ scp)
{
    const int K = 1024;
    __shared__ u16 As[128 * 64];
    __shared__ u16 Bs[128 * 64];
    int bid = blockIdx.x;
    int xcd = bid & 7, sblk = bid >> 3;
    int bn = (xcd & 1) * 12 + sblk % 12;
    int bm = (xcd >> 1) * 8 + sblk / 12;

    int t = threadIdx.x;
    int reg = bn >> 3;   // 0=Q 1=K 2=V
    const u16* A = (reg == 2) ? X : ((gsel[0] * (1.0f / 4096.0f) > 0.3f) ? INV : X);
    const float* bias = (reg == 0) ? bq : (reg == 1) ? bk : bv;
    u16* C = (reg == 0) ? Qb : (reg == 1) ? Kb : Vb;

    int w = t >> 6, lane = t & 63;
    int wr = (w >> 1) * 64, wc = (w & 1) * 64;
    int lr = lane & 15, g = lane >> 4;
    int sw = lr & 7;

    f32x4 zero4 = {0.f, 0.f, 0.f, 0.f};
    f32x4 acc[4][4];
#pragma unroll
    for (int m = 0; m < 4; m++)
#pragma unroll
        for (int n = 0; n < 4; n++) acc[m][n] = zero4;

    int row8 = t >> 3, slot = t & 7;
    int scol = ((slot ^ (row8 & 7)) * 8);
    const u16* ga = A + (size_t)(bm * 128 + row8) * K + scol;
    const u16* gb = Wqkv + (size_t)(bn * 128 + row8) * K + scol;

    for (int k0 = 0; k0 < K; k0 += 64) {
        __syncthreads();
#pragma unroll
        for (int c = 0; c < 4; c++) {
            gll16(ga + (size_t)c * 32 * K + k0, As + c * 2048 + t * 8);
            gll16(gb + (size_t)c * 32 * K + k0, Bs + c * 2048 + t * 8);
        }
        __syncthreads();
#pragma unroll
        for (int kk = 0; kk < 2; kk++) {
            s16x8 af[4], bfr[4];
#pragma unroll
            for (int m = 0; m < 4; m++)
                af[m] = *(const s16x8*)&As[(wr + m * 16 + lr) * 64 + (((kk * 4 + g) ^ sw) * 8)];
#pragma unroll
            for (int n = 0; n < 4; n++)
                bfr[n] = *(const s16x8*)&Bs[(wc + n * 16 + lr) * 64 + (((kk * 4 + g) ^ sw) * 8)];
#pragma unroll
            for (int m = 0; m < 4; m++)
#pragma unroll
                for (int n = 0; n < 4; n++)
                    acc[m][n] = __builtin_amdgcn_mfma_f32_16x16x32_bf16(af[m], bfr[n], acc[m][n], 0, 0, 0);
        }
    }

    int col0 = (bn & 7) * 128 + wc + lr;
    int row0 = bm * 128 + wr + g * 4;
    int bh = (bm >> 3) * 8 + (bn & 7);
#pragma unroll
    for (int n = 0; n < 4; n++) {
        int col = col0 + n * 16;
        float bv = bias[col];
        float colp = 0.f;
#pragma unroll
        for (int m = 0; m < 4; m++)
#pragma unroll
            for (int r = 0; r < 4; r++) {
                float v = acc[m][n][r] + bv;
                colp += v;
                C[(size_t)(row0 + m * 16 + r) * 1024 + col] = f2bf(v);
            }
        if (reg < 2) {
            // reduce over g (rows within wave), then 2 atomics/col/block
            colp += __shfl_xor(colp, 16);
            colp += __shfl_xor(colp, 32);
            if (g == 0)
                atomicAdd(&scp[64 + reg * 4096 + bh * 128 + wc + n * 16 + lr], colp);
        }
    }
}

// ---------- fused W1-GEMM + curvature dots (no C write) ----------
// dots[tok] += sum_cols relu(out@W1+b1)[tok,col] * W2[col]
__global__ __launch_bounds__(256) void gemm_w1c(
    const u16* __restrict__ A, const u16* __restrict__ W, const float* __restrict__ bias,
    const float* __restrict__ W2, float* __restrict__ dots)
{
    const int K = 1024;
    __shared__ u16 As[128 * 64];
    __shared__ u16 Bs[128 * 64];
    int bid = blockIdx.x;
    int xcd = bid & 7, sblk = bid >> 3;           // [0,16)
    int bn = (xcd & 1) * 2 + sblk % 2;            // [0,4)
    int bm = (xcd >> 1) * 8 + sblk / 2;           // [0,32)

    int t = threadIdx.x;
    int w = t >> 6, lane = t & 63;
    int wr = (w >> 1) * 64, wc = (w & 1) * 64;
    int lr = lane & 15, g = lane >> 4;
    int sw = lr & 7;

    f32x4 zero4 = {0.f, 0.f, 0.f, 0.f};
    f32x4 acc[4][4];
#pragma unroll
    for (int m = 0; m < 4; m++)
#pragma unroll
        for (int n = 0; n < 4; n++) acc[m][n] = zero4;

    int row8 = t >> 3, slot = t & 7;
    int scol = ((slot ^ (row8 & 7)) * 8);
    const u16* ga = A + (size_t)(bm * 128 + row8) * K + scol;
    const u16* gb = W + (size_t)(bn * 128 + row8) * K + scol;

    for (int k0 = 0; k0 < K; k0 += 64) {
        __syncthreads();
#pragma unroll
        for (int c = 0; c < 4; c++) {
            gll16(ga + (size_t)c * 32 * K + k0, As + c * 2048 + t * 8);
            gll16(gb + (size_t)c * 32 * K + k0, Bs + c * 2048 + t * 8);
        }
        __syncthreads();
#pragma unroll
        for (int kk = 0; kk < 2; kk++) {
            s16x8 af[4], bfr[4];
#pragma unroll
            for (int m = 0; m < 4; m++)
                af[m] = *(const s16x8*)&As[(wr + m * 16 + lr) * 64 + (((kk * 4 + g) ^ sw) * 8)];
#pragma unroll
            for (int n = 0; n < 4; n++)
                bfr[n] = *(const s16x8*)&Bs[(wc + n * 16 + lr) * 64 + (((kk * 4 + g) ^ sw) * 8)];
#pragma unroll
            for (int m = 0; m < 4; m++)
#pragma unroll
                for (int n = 0; n < 4; n++)
                    acc[m][n] = __builtin_amdgcn_mfma_f32_16x16x32_bf16(af[m], bfr[n], acc[m][n], 0, 0, 0);
        }
    }

    // rowdot[m][r] = sum over this thread's 4 cols of relu(v)*W2[col]
    float rowdot[4][4];
#pragma unroll
    for (int m = 0; m < 4; m++)
#pragma unroll
        for (int r = 0; r < 4; r++) rowdot[m][r] = 0.f;
    int col0 = bn * 128 + wc + lr;
#pragma unroll
    for (int n = 0; n < 4; n++) {
        int col = col0 + n * 16;
        float bv = bias[col];
        float w2v = W2[col];
#pragma unroll
        for (int m = 0; m < 4; m++)
#pragma unroll
            for (int r = 0; r < 4; r++) {
                float v = fmaxf(acc[m][n][r] + bv, 0.0f);
                rowdot[m][r] += v * w2v;
            }
    }
    // reduce across u lanes (cols), then atomicAdd per row from u==0 lanes
    int row0 = bm * 128 + wr + g * 4;
#pragma unroll
    for (int m = 0; m < 4; m++)
#pragma unroll
        for (int r = 0; r < 4; r++) {
            float v = rowdot[m][r];
            v += __shfl_xor(v, 1);
            v += __shfl_xor(v, 2);
            v += __shfl_xor(v, 4);
            v += __shfl_xor(v, 8);
            if (lr == 0) atomicAdd(&dots[row0 + m * 16 + r], v);
        }
}

// ---------- gauge ----------
__global__ __launch_bounds__(256) void gauge_k(const float* __restrict__ xf,
                                               const u16* __restrict__ INV, float* sc) {
    int t = threadIdx.x, w = t >> 6, lane = t & 63;
    float ssum = 0.f;
    for (int rep = 0; rep < 4; rep++) {
        size_t tok = (size_t)blockIdx.x * 16 + w * 4 + rep;
        const float4* xr = (const float4*)(xf + tok * 1024);
        const s16x8* ir = (const s16x8*)(INV + tok * 1024);
        float sr = 0.f, sx = 0.f;
#pragma unroll
        for (int c = 0; c < 2; c++) {
            s16x8 i8 = ir[lane * 2 + c];
            float4 a = xr[lane * 4 + c * 2];
            float4 b = xr[lane * 4 + c * 2 + 1];
            float xv[8] = {a.x, a.y, a.z, a.w, b.x, b.y, b.z, b.w};
#pragma unroll
            for (int e = 0; e < 8; e++) {
                float dv = xv[e] - sbf2f(i8[e]);
                sr += dv * dv; sx += xv[e] * xv[e];
            }
        }
        sr = wredsum(sr); sx = wredsum(sx);
        if (lane == 0) ssum += sqrtf(sr) / (sqrtf(sx) + 1e-8f);
    }
    if (lane == 0) atomicAdd(&sc[0], ssum);
}

// ---------- per-row inv-norm + softmax(dk) for Q,K ----------
__global__ __launch_bounds__(256) void qksm_k(const u16* __restrict__ Qb, const u16* __restrict__ Kb,
                                              u16* __restrict__ QS, u16* __restrict__ KS,
                                              float* __restrict__ RNQ, float* __restrict__ RNK) {
    int t = threadIdx.x, w = t >> 6, lane = t & 63;
    int R = blockIdx.x * 4 + w;
    int isK = R >> 15;
    int r = R & 32767;
    int b = r >> 13, i = (r >> 3) & 1023, h = r & 7;
    int L = b * 8192 + h * 1024 + i;
    const u16* src = (isK ? Kb : Qb) + (size_t)r * 128 + lane * 2;
    u32 uu = *(const u32*)src;
    float q0 = bf2f((u16)(uu & 0xffff)), q1 = bf2f((u16)(uu >> 16));
    float ss = wredsum(q0 * q0 + q1 * q1);
    float rn = 1.0f / fmaxf(sqrtf(ss), 1e-12f);
    if (lane == 0) (isK ? RNK : RNQ)[L] = rn;
    float m = wredmax(fmaxf(q0, q1));
    float e0 = __expf(q0 - m), e1 = __expf(q1 - m);
    float sum = wredsum(e0 + e1);
    float is = 1.0f / sum;
    u32 o = (u32)f2bf(e0 * is) | ((u32)f2bf(e1 * is) << 16);
    *(u32*)((isK ? KS : QS) + (size_t)L * 128 + lane * 2) = o;
}

// ---------- joint entropy: XCD-partitioned, tile-sampled (16 of 64 per bh, x4) ----------
__global__ __launch_bounds__(256) void joint_k(const u16* __restrict__ QS,
                                               const u16* __restrict__ KS, float* sc) {
    __shared__ float red[4];
    int bid = blockIdx.x;
    int xcd = bid & 7, slot = bid >> 3;
    int bh = xcd * 4 + (slot >> 4);
    int rem = slot & 15;
    int it = rem >> 1;
    int jt = (rem & 1) * 4 + (it & 3);
    int t = threadIdx.x;
    int w = t >> 6, lane = t & 63, lr = lane & 15;
    int lk = (lane >> 4) * 8;
    int wr = (w >> 1) * 64, wc = (w & 1) * 64;
    const u16* qg = QS + ((size_t)bh * 1024 + it * 128) * 128;
    const u16* kg = KS + ((size_t)bh * 1024 + jt * 128) * 128;

    f32x4 zero4 = {0.f, 0.f, 0.f, 0.f};
    f32x4 acc[4][4];
#pragma unroll
    for (int m = 0; m < 4; m++)
#pragma unroll
        for (int n = 0; n < 4; n++) acc[m][n] = zero4;
#pragma unroll
    for (int kk = 0; kk < 4; kk++) {
        s16x8 af[4], bfr[4];
#pragma unroll
        for (int m = 0; m < 4; m++)
            af[m] = *(const s16x8*)(qg + (size_t)(wr + m * 16 + lr) * 128 + kk * 32 + lk);
#pragma unroll
        for (int n = 0; n < 4; n++)
            bfr[n] = *(const s16x8*)(kg + (size_t)(wc + n * 16 + lr) * 128 + kk * 32 + lk);
#pragma unroll
        for (int m = 0; m < 4; m++)
#pragma unroll
            for (int n = 0; n < 4; n++)
                acc[m][n] = __builtin_amdgcn_mfma_f32_16x16x32_bf16(af[m], bfr[n], acc[m][n], 0, 0, 0);
    }
    float ts = 0.f;
#pragma unroll
    for (int m = 0; m < 4; m++)
#pragma unroll
        for (int n = 0; n < 4; n++)
#pragma unroll
            for (int r = 0; r < 4; r++) {
                float x = acc[m][n][r];
                ts += x * __logf(fmaxf(x, 0.0f) + 1e-10f);
            }
    ts = wredsum(ts);
    if (lane == 0) red[w] = ts;
    __syncthreads();
    if (t == 0) atomicAdd(&sc[4 + bh], -4.0f * (red[0] + red[1] + red[2] + red[3]));
}

// ---------- gate ----------
__global__ __launch_bounds__(1024) void gate_k(float* sc) {
    __shared__ float Hs[64];
    int t = threadIdx.x;
    int grp = t >> 4, u = t & 15;
    int isK = grp >> 5, idx = grp & 31;
    const float4* cs = (const float4*)(sc + 64 + isK * 4096 + idx * 128 + u * 8);
    float4 a = cs[0], b = cs[1];
    float xv[8] = {a.x, a.y, a.z, a.w, b.x, b.y, b.z, b.w};
    float m = -1e30f;
#pragma unroll
    for (int e = 0; e < 8; e++) m = fmaxf(m, xv[e]);
    m = g16max(m);
    float Z = 0.f, E = 0.f;
#pragma unroll
    for (int e = 0; e < 8; e++) {
        float ex = __expf(xv[e] - m);
        Z += ex; E += ex * (xv[e] - m);
    }
    Z = g16sum(Z); E = g16sum(E);
    if (u == 0) Hs[grp] = __logf(Z) - E / Z;
    __syncthreads();
    if (t < 4) {
        float se = 0.f;
        for (int hh = 0; hh < 8; hh++)
            se += sc[4 + t * 8 + hh] - Hs[t * 8 + hh] - Hs[32 + t * 8 + hh];
        se *= 0.125f;
        sc[36 + t] = (se > 0.15f) ? 1.0f : 0.0f;
    }
}

// ---------- banded QFI attention: MFMA QK^T + scalar PV, XCD-chunked it ----------
#define KVP 136
__global__ __launch_bounds__(256) void attn_k(const u16* __restrict__ Qb, const u16* __restrict__ Kb,
                                              const u16* __restrict__ Vb,
                                              const float* __restrict__ RNQ, const float* __restrict__ RNK,
                                              const float* __restrict__ sc, u16* __restrict__ OUT) {
    __shared__ u16 Kl[96 * KVP];
    __shared__ u16 Vl[96 * KVP];
    __shared__ u16 Ql[32 * KVP];
    __shared__ float Sl[32 * 104];
    __shared__ float rkl[96];
    __shared__ float rql[32];
    int bid = blockIdx.x;
    int xcd = bid & 7, sblk = bid >> 3;
    int it = xcd * 4 + (sblk & 3);
    int hb = sblk >> 2;
    int h = hb & 7, b = hb >> 3;
    int t = threadIdx.x;
    int i0 = it * 32, jbase = i0 - 32;

    for (int c = t; c < 96 * 16; c += 256) {
        int p = c >> 4, x8 = c & 15;
        int j = jbase + p;
        s16x8 kv, vv;
        if (j >= 0 && j < 1024) {
            size_t go = ((size_t)(b * 1024 + j)) * 1024 + h * 128 + x8 * 8;
            kv = *(const s16x8*)(Kb + go);
            vv = *(const s16x8*)(Vb + go);
        } else {
#pragma unroll
            for (int e = 0; e < 8; e++) { kv[e] = 0; vv[e] = 0; }
        }
        *(s16x8*)&Kl[p * KVP + x8 * 8] = kv;
        *(s16x8*)&Vl[p * KVP + x8 * 8] = vv;
    }
    for (int c = t; c < 32 * 16; c += 256) {
        int p = c >> 4, x8 = c & 15;
        size_t go = ((size_t)(b * 1024 + i0 + p)) * 1024 + h * 128 + x8 * 8;
        *(s16x8*)&Ql[p * KVP + x8 * 8] = *(const s16x8*)(Qb + go);
    }
    if (t < 96) {
        int j = jbase + t;
        rkl[t] = (j >= 0 && j < 1024) ? RNK[((size_t)(b * 8 + h)) * 1024 + j] : 0.0f;
    }
    if (t < 32) rql[t] = RNQ[((size_t)(b * 8 + h)) * 1024 + i0 + t];
    __syncthreads();

    int w = t >> 6, lane = t & 63, u = lane & 15, g = lane >> 4;
    int lk = g * 8;

    {
        int mt = w >> 1, nb = (w & 1) * 3;
        f32x4 zero4 = {0.f, 0.f, 0.f, 0.f};
        f32x4 acc[3] = {zero4, zero4, zero4};
#pragma unroll
        for (int kk = 0; kk < 4; kk++) {
            s16x8 af = *(const s16x8*)&Ql[(mt * 16 + u) * KVP + kk * 32 + lk];
#pragma unroll
            for (int nt = 0; nt < 3; nt++) {
                s16x8 bfr = *(const s16x8*)&Kl[((nb + nt) * 16 + u) * KVP + kk * 32 + lk];
                acc[nt] = __builtin_amdgcn_mfma_f32_16x16x32_bf16(af, bfr, acc[nt], 0, 0, 0);
            }
        }
#pragma unroll
        for (int nt = 0; nt < 3; nt++) {
            int Cc = (nb + nt) * 16 + u;
            float rk = rkl[Cc];
#pragma unroll
            for (int r = 0; r < 4; r++) {
                int R = mt * 16 + g * 4 + r;
                float sim = acc[nt][r] * rql[R] * rk;
                float dd = 2.0f * (1.0f - sim);
                dd = fminf(fmaxf(dd, 0.0f), 4.0f);
                Sl[R * 104 + Cc] = -sqrtf(dd);
            }
        }
    }
    __syncthreads();

    float gate = sc[36 + b];
    float factor = gate / (gate + 1e-10f);

    for (int rd = 0; rd < 2; rd++) {
        int il = rd * 16 + w * 4 + g;
        int i = i0 + il;
        int jlo = max(0, i - 32), jhi = min(1023, i + 32);
        int width = jhi - jlo + 1;

        float sv[5];
        float mx = -1e30f;
#pragma unroll
        for (int q5 = 0; q5 < 5; q5++) {
            int sl = u + 16 * q5;
            float sval = (sl < width) ? Sl[il * 104 + (jlo + sl - jbase)] : -1e30f;
            sv[q5] = sval;
            mx = fmaxf(mx, sval);
        }
        mx = g16max(mx);
        float se = 0.f;
#pragma unroll
        for (int q5 = 0; q5 < 5; q5++) {
            float e = (sv[q5] > -1e29f) ? __expf(sv[q5] - mx) : 0.0f;
            sv[q5] = e; se += e;
        }
        se = g16sum(se);
        float isv = 1.0f / se;
#pragma unroll
        for (int q5 = 0; q5 < 5; q5++) {
            int sl = u + 16 * q5;
            if (sl < width) Sl[il * 104 + (jlo + sl - jbase)] = sv[q5] * isv;
        }

        float acc8[8];
#pragma unroll
        for (int e = 0; e < 8; e++) acc8[e] = 0.f;
        for (int sl = 0; sl < width; sl++) {
            int p = jlo + sl - jbase;
            float wj = Sl[il * 104 + p];
            s16x8 v8 = *(const s16x8*)&Vl[p * KVP + u * 8];
#pragma unroll
            for (int e = 0; e < 8; e++) acc8[e] += wj * sbf2f(v8[e]);
        }
        size_t oo = ((size_t)(b * 1024 + i)) * 1024 + h * 128 + u * 8;
        s16x8 o8;
#pragma unroll
        for (int e = 0; e < 8; e++) o8[e] = (short)f2bf(acc8[e] * factor);
        *(s16x8*)(OUT + oo) = o8;
    }
}

// ---------- host-side launch ----------
extern "C" void kernel_launch(void* const* d_in, const int* in_sizes, int n_in,
                              void* d_out, int out_size, void* d_ws, size_t ws_size,
                              hipStream_t stream) {
    const float* xf  = (const float*)d_in[0];
    const float* Wq  = (const float*)d_in[1];
    const float* bq  = (const float*)d_in[2];
    const float* Wk  = (const float*)d_in[3];
    const float* bk_ = (const float*)d_in[4];
    const float* Wv  = (const float*)d_in[5];
    const float* bv  = (const float*)d_in[6];
    const float* Wo  = (const float*)d_in[7];
    const float* bo  = (const float*)d_in[8];
    const float* Wp  = (const float*)d_in[9];
    const float* bp  = (const float*)d_in[10];
    const float* W1  = (const float*)d_in[11];
    const float* b1  = (const float*)d_in[12];
    const float* W2  = (const float*)d_in[13];
    const float* b2  = (const float*)d_in[14];
    float* out = (float*)d_out;

    uint8_t* ws = (uint8_t*)d_ws;
    float* sc  = (float*)ws;
    u16* BF    = (u16*)(ws + 0x0010000);
    u16* xbf   = BF;
    u16* Wqb   = BF + 4194304;
    u16* Wob   = BF + 7340032;
    u16* Wpb   = BF + 8388608;
    u16* W1b   = BF + 9437184;
    u16* INV   = (u16*)(ws + 0x1410000);
    u16* Qb    = (u16*)(ws + 0x1C10000);
    u16* Kb    = (u16*)(ws + 0x2410000);
    u16* Vb    = (u16*)(ws + 0x2C10000);
    u16* KS    = (u16*)(ws + 0x3410000);
    float* RNQ = (float*)(ws + 0x3C10000);
    float* RNK = (float*)(ws + 0x3C30000);
    u16* QS    = INV;
    u16* OUTb  = KS;
    float* dots = sc + DOTS_OFF;

    cvt7_k<<<dim3(4096, 7), 256, 0, stream>>>(xf, Wq, Wk, Wv, Wo, Wp, W1, BF, sc);
    gemm_bt<<<256, 256, 0, stream>>>(xbf, nullptr, nullptr, Wpb, bp, INV, 1024, 1024, 0, 0, 8,
                                     0, nullptr, nullptr);
    gauge_k<<<256, 256, 0, stream>>>(xf, INV, sc);
    gemm_qkv<<<768, 256, 0, stream>>>(xbf, INV, sc, Wqb, bq, bk_, bv, Qb, Kb, Vb, sc);
    qksm_k<<<16384, 256, 0, stream>>>(Qb, Kb, QS, KS, RNQ, RNK);
    joint_k<<<512, 256, 0, stream>>>(QS, KS, sc);
    gate_k<<<1, 1024, 0, stream>>>(sc);
    attn_k<<<1024, 256, 0, stream>>>(Qb, Kb, Vb, RNQ, RNK, sc, OUTb);
    gemm_w1c<<<128, 256, 0, stream>>>(OUTb, W1b, b1, W2, dots);
    gemm_bt<<<256, 256, 0, stream>>>(OUTb, nullptr, nullptr, Wob, bo, out, 1024, 1024, 0, 1, 8,
                                     1, dots, b2);
    (void)in_sizes; (void)n_in; (void)out_size; (void)ws_size;
}